// Round 10
// baseline (1041.942 us; speedup 1.0000x reference)
//
#include <hip/hip_runtime.h>

typedef unsigned short u16;
typedef unsigned int u32;
typedef __attribute__((ext_vector_type(8))) short bf16x8;
typedef __attribute__((ext_vector_type(4))) float f32x4;

#define MFMA(a, b, c) __builtin_amdgcn_mfma_f32_16x16x32_bf16(a, b, c, 0, 0, 0)

__device__ __forceinline__ u16 f2bf(float x) {
    union { float f; u32 u; } v; v.f = x;
    u32 r = (v.u + 0x7FFFu + ((v.u >> 16) & 1u)) >> 16;
    return (u16)r;
}
__device__ __forceinline__ float bf2f(u16 b) {
    union { u32 u; float f; } v; v.u = ((u32)b) << 16;
    return v.f;
}
__device__ __forceinline__ void casAddPair(u32* w, float lo, float hi) {
    u32 old = *w, assumed;
    do {
        assumed = old;
        u32 des = (u32)f2bf(bf2f((u16)(assumed & 0xFFFFu)) + lo) |
                  ((u32)f2bf(bf2f((u16)(assumed >> 16)) + hi) << 16);
        if (des == assumed) break;
        old = atomicCAS(w, assumed, des);
    } while (old != assumed);
}

// ---------------------------------------------------------------------------
// prep: convert LSTM weights to bf16 (gate rows pre-scaled by log2e, g-gate by
// 2*log2e for native v_exp_f32), combine biases, and pre-convert the other
// weight matrices to bf16 so per-block staging is pure vector copies.
__global__ __launch_bounds__(256) void prep_w(
    const float* __restrict__ Whh_f, const float* __restrict__ Whh_b,
    const float* __restrict__ Wih_f, const float* __restrict__ Wih_b,
    const float* __restrict__ bih_f, const float* __restrict__ bhh_f,
    const float* __restrict__ bih_b, const float* __restrict__ bhh_b,
    const float* __restrict__ W_feat, const float* __restrict__ W_msg,
    const float* __restrict__ W_msg_l, const float* __restrict__ W_lg2g,
    u16* __restrict__ WhhB, u16* __restrict__ WihB, float* __restrict__ BS,
    u16* __restrict__ WfeatB, u16* __restrict__ WmsgB,
    u16* __restrict__ WmsgLB, u16* __restrict__ Wlg2gB)
{
    const float L2E = 1.4426950408889634f;
    int i = blockIdx.x * 256 + threadIdx.x;
    if (i < 131072) {
        int d = i >> 16, r = i & 65535;
        float s = (((r >> 14) & 3) == 2) ? 2.f * L2E : L2E;
        WhhB[i] = f2bf(s * (d ? Whh_b[r] : Whh_f[r]));
    } else if (i < 196608) {
        int i2 = i - 131072; int d = i2 >> 15, r = i2 & 32767;
        float s = (((r >> 13) & 3) == 2) ? 2.f * L2E : L2E;
        WihB[i2] = f2bf(s * (d ? Wih_b[r] : Wih_f[r]));
    } else if (i < 197632) {
        int i3 = i - 196608; int d = i3 >> 9, g = i3 & 511;
        float s = (((g >> 7) & 3) == 2) ? 2.f * L2E : L2E;
        BS[i3] = s * (d ? (bih_b[g] + bhh_b[g]) : (bih_f[g] + bhh_f[g]));
    } else if (i < 205824) {
        int j = i - 197632; WfeatB[j] = f2bf(W_feat[j]);
    } else if (i < 215040) {
        int j = i - 205824; WmsgB[j] = f2bf(W_msg[j]);
    } else if (i < 233472) {
        int j = i - 215040; WmsgLB[j] = f2bf(W_msg_l[j]);
    } else if (i < 237568) {
        int j = i - 233472; Wlg2gB[j] = f2bf(W_lg2g[j]);
    }
}

// ---------------------------------------------------------------------------
// CSR build — both graphs counted / filled in single launches (independent
// atomics in flight; 2 launches saved).
__global__ __launch_bounds__(256) void count2(
    const int* __restrict__ dg, u32* __restrict__ cg, long Eg,
    const int* __restrict__ dl, u32* __restrict__ cl, long El)
{
    long i = (long)blockIdx.x * 256 + threadIdx.x;
    if (i < Eg) atomicAdd(&cg[dg[i]], 1u);
    if (i < El) atomicAdd(&cl[dl[i]], 1u);
}

__global__ __launch_bounds__(256) void fill2(
    const int* __restrict__ dg, u32* __restrict__ og, int* __restrict__ lg_,
    long Eg,
    const int* __restrict__ dl, u32* __restrict__ ol, int* __restrict__ ll,
    long El)
{
    long i = (long)blockIdx.x * 256 + threadIdx.x;
    if (i < Eg) { u32 p = atomicAdd(&og[dg[i]], 1u); lg_[p] = (int)i; }
    if (i < El) { u32 p = atomicAdd(&ol[dl[i]], 1u); ll[p] = (int)i; }
}

__global__ __launch_bounds__(256) void scan1(const u32* __restrict__ a,
                                             u32* __restrict__ part, int n)
{
    __shared__ u32 ts[256];
    int b = blockIdx.x, t = threadIdx.x;
    long i0 = (long)b * 1024 + t * 4;
    u32 s = 0;
#pragma unroll
    for (int k = 0; k < 4; ++k) { long i = i0 + k; if (i < n) s += a[i]; }
    ts[t] = s; __syncthreads();
    for (int off = 1; off < 256; off <<= 1) {
        u32 x = (t >= off) ? ts[t - off] : 0u;
        __syncthreads(); ts[t] += x; __syncthreads();
    }
    if (t == 255) part[b] = ts[255];
}

__global__ __launch_bounds__(1024) void scan2(u32* __restrict__ part, int nb,
                                              u32* __restrict__ total_out)
{
    __shared__ u32 ts[1024];
    int t = threadIdx.x;
    u32 v = (t < nb) ? part[t] : 0u;
    ts[t] = v; __syncthreads();
    for (int off = 1; off < 1024; off <<= 1) {
        u32 x = (t >= off) ? ts[t - off] : 0u;
        __syncthreads(); ts[t] += x; __syncthreads();
    }
    if (t < nb) part[t] = ts[t] - v;
    if (t == 1023 && total_out) *total_out = ts[1023];
}

__global__ __launch_bounds__(256) void scan3(u32* __restrict__ a,
                                             const u32* __restrict__ part, int n)
{
    __shared__ u32 ts[256];
    int b = blockIdx.x, t = threadIdx.x;
    long i0 = (long)b * 1024 + t * 4;
    u32 v[4]; u32 s = 0;
#pragma unroll
    for (int k = 0; k < 4; ++k) { long i = i0 + k; v[k] = (i < n) ? a[i] : 0u; s += v[k]; }
    ts[t] = s; __syncthreads();
    for (int off = 1; off < 256; off <<= 1) {
        u32 x = (t >= off) ? ts[t - off] : 0u;
        __syncthreads(); ts[t] += x; __syncthreads();
    }
    u32 run = part[b] + ts[t] - s;
#pragma unroll
    for (int k = 0; k < 4; ++k) {
        long i = i0 + k;
        if (i < n) { u32 x = v[k]; a[i] = run; run += x; }
    }
}

// ---------------------------------------------------------------------------
__global__ __launch_bounds__(256) void zero_fill(const u32* __restrict__ offc,
                                                 u16* __restrict__ outb, long NB)
{
    long idx = (long)blockIdx.x * 256 + threadIdx.x;
    long n = idx >> 3; int q = (int)(idx & 7);
    if (n >= NB) return;
    u32 s = n ? offc[n - 1] : 0u;
    u32 e = offc[n];
    bool need = (s == e) || ((s >> 7) != ((e - 1) >> 7));
    if (need) *(uint4*)(outb + n * 64 + q * 8) = make_uint4(0, 0, 0, 0);
}

// ---------------------------------------------------------------------------
// rowgemm: outb[M x 64] (bf16) = act(in[M x K] @ W[64 x K]^T (+ bias*scale))
template <int K, bool RELU, bool INBF16>
__global__ __launch_bounds__(256) void rowgemm(
    const void* __restrict__ in, const u16* __restrict__ W,
    const float* __restrict__ bias, const float* __restrict__ bias_scale,
    u16* __restrict__ outb, int M)
{
    constexpr int KP = K + 8;
    constexpr int K8 = K / 8;
    __shared__ u16 inS[64 * KP];
    __shared__ u16 WS[64 * KP];
    int t = threadIdx.x;
    long rb = (long)blockIdx.x * 64;
    for (int i = t; i < 64 * K8; i += 256) {
        int c = i / K8, q = i - c * K8;
        *(uint4*)&WS[c * KP + q * 8] = *(const uint4*)&W[c * K + q * 8];
    }
    if (INBF16) {
        const u16* inb = (const u16*)in;
        for (int i = t; i < 64 * K8; i += 256) {
            int r = i / K8, q = i - r * K8;
            long gr = rb + r;
            uint4 v = make_uint4(0, 0, 0, 0);
            if (gr < M) v = *(const uint4*)&inb[gr * (long)K + q * 8];
            *(uint4*)&inS[r * KP + q * 8] = v;
        }
    } else {
        const float* inf = (const float*)in;
        for (int i = t; i < 64 * K; i += 256) {
            int r = i / K, k = i - r * K;
            long gr = rb + r;
            inS[r * KP + k] = (gr < M) ? f2bf(inf[gr * (long)K + k]) : (u16)0;
        }
    }
    __syncthreads();
    int l = t & 63, w = t >> 6, lr = l & 15, lq = l >> 4;
    f32x4 acc[4];
#pragma unroll
    for (int i = 0; i < 4; ++i) acc[i] = (f32x4){0.f, 0.f, 0.f, 0.f};
#pragma unroll
    for (int kc = 0; kc < K; kc += 32) {
        bf16x8 a = *(const bf16x8*)&inS[(w * 16 + lr) * KP + kc + lq * 8];
#pragma unroll
        for (int ct = 0; ct < 4; ++ct) {
            bf16x8 b = *(const bf16x8*)&WS[(ct * 16 + lr) * KP + kc + lq * 8];
            acc[ct] = MFMA(a, b, acc[ct]);
        }
    }
#pragma unroll
    for (int ct = 0; ct < 4; ++ct)
#pragma unroll
        for (int r = 0; r < 4; ++r) {
            long gr = rb + w * 16 + lq * 4 + r;
            if (gr < M) {
                int c = ct * 16 + lr;
                float v = acc[ct][r];
                if (bias) v += bias[c] * (bias_scale ? bias_scale[gr] : 1.f);
                if (RELU) v = fmaxf(v, 0.f);
                outb[gr * 64 + c] = f2bf(v);
            }
        }
}

// ---------------------------------------------------------------------------
// edge_msg_init2: direct-gather A-fragments; W pre-converted bf16, attr f32.
__global__ __launch_bounds__(512, 4) void edge_msg_init2(
    const u16* __restrict__ feat, const int* __restrict__ ei,
    const float* __restrict__ attr, const u16* __restrict__ W,
    u16* __restrict__ outb, long E)
{
    __shared__ u16 WS[64 * 168];
    __shared__ u16 eds[128 * 64];
    int t = threadIdx.x;
    long eb = (long)blockIdx.x * 128;
    int w = t >> 6, l = t & 63, lr = l & 15, lq = l >> 4;
    long e = eb + w * 16 + lr;
    long ec = (e < E) ? e : (E - 1);
    int src = ei[ec], dst = ei[E + ec];
    bf16x8 A[5];
    {
        const uint4* sp = (const uint4*)(feat + (long)src * 64);
        const uint4* dp = (const uint4*)(feat + (long)dst * 64);
        *(uint4*)&A[0] = sp[lq];
        *(uint4*)&A[1] = sp[4 + lq];
        *(uint4*)&A[2] = dp[lq];
        *(uint4*)&A[3] = dp[4 + lq];
        uint4 pv = make_uint4(0, 0, 0, 0);
        if (lq < 2) {
            const float4* ap = (const float4*)(attr + ec * 16) + lq * 2;
            float4 b0 = ap[0], b1 = ap[1];
            pv.x = (u32)f2bf(b0.x) | ((u32)f2bf(b0.y) << 16);
            pv.y = (u32)f2bf(b0.z) | ((u32)f2bf(b0.w) << 16);
            pv.z = (u32)f2bf(b1.x) | ((u32)f2bf(b1.y) << 16);
            pv.w = (u32)f2bf(b1.z) | ((u32)f2bf(b1.w) << 16);
        }
        *(uint4*)&A[4] = pv;
    }
    for (int i = t; i < 1152; i += 512) {                 // 64*144/8
        int c = i / 18, q = i - c * 18;
        *(uint4*)&WS[c * 168 + q * 8] = *(const uint4*)&W[c * 144 + q * 8];
    }
    if (t < 192) {                                        // 64*24/8 zero pad
        int c = t / 3, q = t - c * 3;
        *(uint4*)&WS[c * 168 + 144 + q * 8] = make_uint4(0, 0, 0, 0);
    }
    __syncthreads();
    f32x4 acc[4];
#pragma unroll
    for (int ct = 0; ct < 4; ++ct) acc[ct] = (f32x4){0.f, 0.f, 0.f, 0.f};
#pragma unroll
    for (int kc = 0; kc < 5; ++kc) {
#pragma unroll
        for (int ct = 0; ct < 4; ++ct) {
            bf16x8 b = *(const bf16x8*)&WS[(ct * 16 + lr) * 168 + kc * 32 + lq * 8];
            acc[ct] = MFMA(A[kc], b, acc[ct]);
        }
    }
#pragma unroll
    for (int ct = 0; ct < 4; ++ct)
#pragma unroll
        for (int r = 0; r < 4; ++r) {
            int row = w * 16 + lq * 4 + r;
            int col = ct * 16 + lr;
            eds[row * 64 + col] = f2bf(fmaxf(acc[ct][r], 0.f));
        }
    __syncthreads();
    for (int j = t; j < 1024; j += 512) {
        int le = j >> 3, q = j & 7;
        long e2 = eb + le;
        if (e2 < E)
            *(uint4*)(outb + e2 * 64 + q * 8) = *(const uint4*)&eds[le * 64 + q * 8];
    }
}

// ---------------------------------------------------------------------------
// edge_msg_lg2: dst-sorted (CSR) order, segmented reduction epilogue.
// Per-thread id/src/dst now read DIRECTLY from global (list/ei, L1-broadcast
// across lq duplicates) so the ~600-cy L3 feature gathers issue immediately,
// overlapping the WS staging + barrier instead of waiting behind them.
// dstS staged only for the epilogue segment scan.
__global__ __launch_bounds__(512, 4) void edge_msg_lg2(
    const u16* __restrict__ feat, const int* __restrict__ ei,
    const float* __restrict__ attr, const u16* __restrict__ W,
    const int* __restrict__ list, u16* __restrict__ outb, long E)
{
    __shared__ u16 WS[64 * 168];
    __shared__ u16 eds[128 * 64];
    __shared__ int dstS[128];
    __shared__ int dprevS, dnextS;
    int t = threadIdx.x;
    long pb = (long)blockIdx.x * 128;
    int w = t >> 6, l = t & 63, lr = l & 15, lq = l >> 4;
    int el = w * 16 + lr;
    long p = pb + el;
    int id = (p < E) ? list[p] : -1;
    long idc = (id >= 0) ? (long)id : 0;
    int src = (id >= 0) ? ei[idc] : 0;
    int dst = (id >= 0) ? ei[E + idc] : 0;
    bf16x8 A[5];
    {
        const uint4* sp = (const uint4*)(feat + (long)src * 64);
        const uint4* dp = (const uint4*)(feat + (long)dst * 64);
        *(uint4*)&A[0] = sp[lq];
        *(uint4*)&A[1] = sp[4 + lq];
        *(uint4*)&A[2] = dp[lq];
        *(uint4*)&A[3] = dp[4 + lq];
        uint4 pv = make_uint4(0, 0, 0, 0);
        if (lq < 2) {
            const float4* ap = (const float4*)(attr + idc * 16) + lq * 2;
            float4 b0 = ap[0], b1 = ap[1];
            pv.x = (u32)f2bf(b0.x) | ((u32)f2bf(b0.y) << 16);
            pv.y = (u32)f2bf(b0.z) | ((u32)f2bf(b0.w) << 16);
            pv.z = (u32)f2bf(b1.x) | ((u32)f2bf(b1.y) << 16);
            pv.w = (u32)f2bf(b1.z) | ((u32)f2bf(b1.w) << 16);
        }
        *(uint4*)&A[4] = pv;
    }
    for (int i = t; i < 1152; i += 512) {
        int c = i / 18, q = i - c * 18;
        *(uint4*)&WS[c * 168 + q * 8] = *(const uint4*)&W[c * 144 + q * 8];
    }
    if (t < 192) {
        int c = t / 3, q = t - c * 3;
        *(uint4*)&WS[c * 168 + 144 + q * 8] = make_uint4(0, 0, 0, 0);
    }
    if (t < 128) {
        long p2 = pb + t;
        int id2 = (p2 < E) ? list[p2] : -1;
        dstS[t] = (id2 >= 0) ? ei[E + id2] : -1;
    } else if (t == 128) {
        dprevS = (pb > 0) ? ei[E + list[pb - 1]] : -2;
    } else if (t == 129) {
        dnextS = (pb + 128 < E) ? ei[E + list[pb + 128]] : -2;
    }
    f32x4 acc[4];
#pragma unroll
    for (int ct = 0; ct < 4; ++ct) acc[ct] = (f32x4){0.f, 0.f, 0.f, 0.f};
    __syncthreads();
#pragma unroll
    for (int kc = 0; kc < 5; ++kc) {
#pragma unroll
        for (int ct = 0; ct < 4; ++ct) {
            bf16x8 b = *(const bf16x8*)&WS[(ct * 16 + lr) * 168 + kc * 32 + lq * 8];
            acc[ct] = MFMA(A[kc], b, acc[ct]);
        }
    }
#pragma unroll
    for (int ct = 0; ct < 4; ++ct)
#pragma unroll
        for (int r = 0; r < 4; ++r) {
            int row = w * 16 + lq * 4 + r;
            int col = ct * 16 + lr;
            eds[row * 64 + col] = f2bf(fmaxf(acc[ct][r], 0.f));
        }
    __syncthreads();
    for (int j = t; j < 4096; j += 512) {
        int le = j >> 5, wd = j & 31;
        int d = dstS[le];
        if (d < 0) continue;
        if (le > 0 && dstS[le - 1] == d) continue;
        float lo = 0.f, hi = 0.f;
        int le2 = le;
        do {
            u32 pair = *(const u32*)&eds[le2 * 64 + wd * 2];
            lo += bf2f((u16)(pair & 0xFFFFu));
            hi += bf2f((u16)(pair >> 16));
            ++le2;
        } while (le2 < 128 && dstS[le2] == d);
        bool bprev = (le == 0 && dprevS == d);
        bool bnext = (le2 == 128 && dnextS == d);
        u32* dw = (u32*)(outb + (long)d * 64 + wd * 2);
        if (bprev || bnext) {
            casAddPair(dw, lo, hi);
        } else {
            *dw = (u32)f2bf(lo) | ((u32)f2bf(hi) << 16);
        }
    }
}

// ---------------------------------------------------------------------------
// gather_gw: FUSED gather + 64x64 linear. One wave per node (halves do
// even/odd list positions); 8-deep manual unroll keeps 8 independent L3
// line-reads in flight per half-wave (avg degree 16 -> one full iteration).
// f32 agg -> LDS -> 64-lane matvec vs transposed W (pad 66).
__global__ __launch_bounds__(256) void gather_gw(
    const u16* __restrict__ m, const int* __restrict__ list,
    const u32* __restrict__ offc, const u16* __restrict__ Wg,
    const float* __restrict__ bias, int useDeg,
    u16* __restrict__ outb, int N)
{
    __shared__ u16 WS[64 * 66];       // transposed: WS[k*66+r] = W[r][k]
    __shared__ float aggS[4][64];
    __shared__ float degS[4];
    int t = threadIdx.x;
    for (int i = t; i < 4096; i += 256) {
        int r = i >> 6, k = i & 63;
        WS[k * 66 + r] = Wg[i];
    }
    int wv = t >> 6, l = t & 63, c = l & 31, half = l >> 5;
    long n = (long)blockIdx.x * 4 + wv;
    long nn = (n < N) ? n : (long)(N - 1);
    u32 start = nn ? offc[nn - 1] : 0u;
    u32 end = offc[nn];
    float s0 = 0.f, s1 = 0.f, s2 = 0.f, s3 = 0.f;
    float s4 = 0.f, s5 = 0.f, s6 = 0.f, s7 = 0.f;
    float t0 = 0.f, t1 = 0.f, t2 = 0.f, t3 = 0.f;
    float t4 = 0.f, t5 = 0.f, t6 = 0.f, t7 = 0.f;
    u32 i = start + half;
    for (; i + 14 < end; i += 16) {   // 8 stride-2 elems per half-wave
        int e0 = list[i],      e1 = list[i + 2],  e2 = list[i + 4],  e3 = list[i + 6];
        int e4 = list[i + 8],  e5 = list[i + 10], e6 = list[i + 12], e7 = list[i + 14];
        u32 p0 = *(const u32*)&m[(long)e0 * 64 + c * 2];
        u32 p1 = *(const u32*)&m[(long)e1 * 64 + c * 2];
        u32 p2 = *(const u32*)&m[(long)e2 * 64 + c * 2];
        u32 p3 = *(const u32*)&m[(long)e3 * 64 + c * 2];
        u32 p4 = *(const u32*)&m[(long)e4 * 64 + c * 2];
        u32 p5 = *(const u32*)&m[(long)e5 * 64 + c * 2];
        u32 p6 = *(const u32*)&m[(long)e6 * 64 + c * 2];
        u32 p7 = *(const u32*)&m[(long)e7 * 64 + c * 2];
        s0 += bf2f((u16)(p0 & 0xFFFFu)); t0 += bf2f((u16)(p0 >> 16));
        s1 += bf2f((u16)(p1 & 0xFFFFu)); t1 += bf2f((u16)(p1 >> 16));
        s2 += bf2f((u16)(p2 & 0xFFFFu)); t2 += bf2f((u16)(p2 >> 16));
        s3 += bf2f((u16)(p3 & 0xFFFFu)); t3 += bf2f((u16)(p3 >> 16));
        s4 += bf2f((u16)(p4 & 0xFFFFu)); t4 += bf2f((u16)(p4 >> 16));
        s5 += bf2f((u16)(p5 & 0xFFFFu)); t5 += bf2f((u16)(p5 >> 16));
        s6 += bf2f((u16)(p6 & 0xFFFFu)); t6 += bf2f((u16)(p6 >> 16));
        s7 += bf2f((u16)(p7 & 0xFFFFu)); t7 += bf2f((u16)(p7 >> 16));
    }
    for (; i + 6 < end; i += 8) {     // 4-deep tail
        int e0 = list[i], e1 = list[i + 2], e2 = list[i + 4], e3 = list[i + 6];
        u32 p0 = *(const u32*)&m[(long)e0 * 64 + c * 2];
        u32 p1 = *(const u32*)&m[(long)e1 * 64 + c * 2];
        u32 p2 = *(const u32*)&m[(long)e2 * 64 + c * 2];
        u32 p3 = *(const u32*)&m[(long)e3 * 64 + c * 2];
        s0 += bf2f((u16)(p0 & 0xFFFFu)); t0 += bf2f((u16)(p0 >> 16));
        s1 += bf2f((u16)(p1 & 0xFFFFu)); t1 += bf2f((u16)(p1 >> 16));
        s2 += bf2f((u16)(p2 & 0xFFFFu)); t2 += bf2f((u16)(p2 >> 16));
        s3 += bf2f((u16)(p3 & 0xFFFFu)); t3 += bf2f((u16)(p3 >> 16));
    }
    for (; i < end; i += 2) {
        int e = list[i];
        u32 pair = *(const u32*)&m[(long)e * 64 + c * 2];
        s0 += bf2f((u16)(pair & 0xFFFFu));
        t0 += bf2f((u16)(pair >> 16));
    }
    float slo = ((s0 + s1) + (s2 + s3)) + ((s4 + s5) + (s6 + s7));
    float shi = ((t0 + t1) + (t2 + t3)) + ((t4 + t5) + (t6 + t7));
    slo += __shfl_xor(slo, 32);
    shi += __shfl_xor(shi, 32);
    if (half == 0) { aggS[wv][c * 2] = slo; aggS[wv][c * 2 + 1] = shi; }
    if (l == 0) degS[wv] = (float)(end - start);
    __syncthreads();
    float acc = 0.f;
#pragma unroll 8
    for (int k = 0; k < 64; ++k)
        acc += aggS[wv][k] * bf2f(WS[k * 66 + l]);
    float scale = useDeg ? degS[wv] : 1.f;
    acc += bias[l] * scale;
    if (n < N) outb[n * 64 + l] = f2bf(acc);
}

// ---------------------------------------------------------------------------
// lstm3: bidirectional JK-LSTM, 64 nodes/tile — round-2's proven all-LDS
// dataflow (159 us, VGPR 108, no spill). Structurally done: Wh (64 regs) +
// acc AGPRs put total regs ~172 -> hard 2 waves/SIMD; Whh (128 KB/dir)
// cannot be LDS-resident, so 4 waves/SIMD without spill is infeasible.
__global__ __launch_bounds__(512, 2) void lstm3(
    const u16* __restrict__ jkB, const u16* __restrict__ WhhB,
    const u16* __restrict__ WihB, const float* __restrict__ BS,
    const float* __restrict__ Watt, float* __restrict__ scores,
    int N)
{
    __shared__ u16 hS[64 * 136];         // 17408 B
    __shared__ u16 xS[4][64 * 72];       // 36864 B
    __shared__ u16 WiS[512 * 72];        // 73728 B (padded stride 72)
    __shared__ float bsS[512];           //  2048 B
    __shared__ float part[4 * 64 * 8];   //  8192 B   total 138240 B
    int t = threadIdx.x;
    int dir = blockIdx.y;
    int w = t >> 6, l = t & 63, lr = l & 15, lq = l >> 4;
    const u16* WhhD = WhhB + (long)dir * 65536;
    const u16* WihD = WihB + (long)dir * 32768;
    long n0 = (long)blockIdx.x * 64;

    // stage x for all 4 JK steps
    {
        int n = t >> 3, j = t & 7;
        long gn = n0 + n;
#pragma unroll
        for (int k = 0; k < 4; ++k) {
            uint4 v = make_uint4(0, 0, 0, 0);
            if (gn < N) v = *(const uint4*)&jkB[((long)k * N + gn) * 64 + j * 8];
            *(uint4*)&xS[k][n * 72 + j * 8] = v;
        }
    }
    // stage Wi (512 gate-rows x 64, padded to 72) and bias
#pragma unroll
    for (int i = t; i < 4096; i += 512) {
        int g = i >> 3, q = i & 7;
        *(uint4*)&WiS[g * 72 + q * 8] = *(const uint4*)&WihD[g * 64 + q * 8];
    }
    bsS[t] = BS[dir * 512 + t];

    int grow0 = w * 16 + lq * 4;         // this thread's first hidden unit
    bf16x8 Wh[4][4];
#pragma unroll
    for (int ty = 0; ty < 4; ++ty) {
        int g = ty * 128 + w * 16 + lr;
#pragma unroll
        for (int kc = 0; kc < 4; ++kc)
            Wh[ty][kc] = *(const bf16x8*)&WhhD[g * 128 + kc * 32 + lq * 8];
    }
    float4 Wa4 = *(const float4*)&Watt[dir * 128 + grow0];
    float* scOut = scores + (long)dir * N * 4;

    float creg[4][4] = {};
    __syncthreads();                     // xS / WiS / bsS visible

#pragma unroll 1
    for (int s = 0; s < 4; ++s) {
        int tt = dir ? (3 - s) : s;
        float u[4][4];
        // ---------------- pass A: gates i (0) and g (2) -> u ----------------
        {
            f32x4 acc[2][4];
            f32x4 bi = *(const f32x4*)&bsS[grow0];
            f32x4 bg = *(const f32x4*)&bsS[256 + grow0];
#pragma unroll
            for (int nt = 0; nt < 4; ++nt) { acc[0][nt] = bi; acc[1][nt] = bg; }
            if (s) {
#pragma unroll
                for (int kc = 0; kc < 4; ++kc) {
                    bf16x8 a[4];
#pragma unroll
                    for (int nt = 0; nt < 4; ++nt)
                        a[nt] = *(const bf16x8*)&hS[(nt * 16 + lr) * 136 + kc * 32 + lq * 8];
#pragma unroll
                    for (int nt = 0; nt < 4; ++nt) {
                        acc[0][nt] = MFMA(Wh[0][kc], a[nt], acc[0][nt]);
                        acc[1][nt] = MFMA(Wh[2][kc], a[nt], acc[1][nt]);
                    }
                }
            }
#pragma unroll
            for (int kc = 0; kc < 2; ++kc) {
                bf16x8 wi = *(const bf16x8*)&WiS[(w * 16 + lr) * 72 + kc * 32 + lq * 8];
                bf16x8 wg = *(const bf16x8*)&WiS[(256 + w * 16 + lr) * 72 + kc * 32 + lq * 8];
                bf16x8 a[4];
#pragma unroll
                for (int nt = 0; nt < 4; ++nt)
                    a[nt] = *(const bf16x8*)&xS[tt][(nt * 16 + lr) * 72 + kc * 32 + lq * 8];
#pragma unroll
                for (int nt = 0; nt < 4; ++nt) {
                    acc[0][nt] = MFMA(wi, a[nt], acc[0][nt]);
                    acc[1][nt] = MFMA(wg, a[nt], acc[1][nt]);
                }
            }
#pragma unroll
            for (int nt = 0; nt < 4; ++nt)
#pragma unroll
                for (int r = 0; r < 4; ++r) {
                    float si = __builtin_amdgcn_rcpf(
                        1.f + __builtin_amdgcn_exp2f(-acc[0][nt][r]));
                    float tg = 2.f * __builtin_amdgcn_rcpf(
                        1.f + __builtin_amdgcn_exp2f(-acc[1][nt][r])) - 1.f;
                    u[nt][r] = si * tg;
                }
        }
        // ---------------- pass B: gates f (1) and o (3) -> c, h -------------
        {
            f32x4 acc[2][4];
            f32x4 bf = *(const f32x4*)&bsS[128 + grow0];
            f32x4 bo = *(const f32x4*)&bsS[384 + grow0];
#pragma unroll
            for (int nt = 0; nt < 4; ++nt) { acc[0][nt] = bf; acc[1][nt] = bo; }
            if (s) {
#pragma unroll
                for (int kc = 0; kc < 4; ++kc) {
                    bf16x8 a[4];
#pragma unroll
                    for (int nt = 0; nt < 4; ++nt)
                        a[nt] = *(const bf16x8*)&hS[(nt * 16 + lr) * 136 + kc * 32 + lq * 8];
#pragma unroll
                    for (int nt = 0; nt < 4; ++nt) {
                        acc[0][nt] = MFMA(Wh[1][kc], a[nt], acc[0][nt]);
                        acc[1][nt] = MFMA(Wh[3][kc], a[nt], acc[1][nt]);
                    }
                }
            }
#pragma unroll
            for (int kc = 0; kc < 2; ++kc) {
                bf16x8 wf = *(const bf16x8*)&WiS[(128 + w * 16 + lr) * 72 + kc * 32 + lq * 8];
                bf16x8 wo = *(const bf16x8*)&WiS[(384 + w * 16 + lr) * 72 + kc * 32 + lq * 8];
                bf16x8 a[4];
#pragma unroll
                for (int nt = 0; nt < 4; ++nt)
                    a[nt] = *(const bf16x8*)&xS[tt][(nt * 16 + lr) * 72 + kc * 32 + lq * 8];
#pragma unroll
                for (int nt = 0; nt < 4; ++nt) {
                    acc[0][nt] = MFMA(wf, a[nt], acc[0][nt]);
                    acc[1][nt] = MFMA(wo, a[nt], acc[1][nt]);
                }
            }
            if (s) __syncthreads();      // all hS reads (A+B) done before overwrite
#pragma unroll
            for (int nt = 0; nt < 4; ++nt) {
                float hv[4];
#pragma unroll
                for (int r = 0; r < 4; ++r) {
                    float sf = __builtin_amdgcn_rcpf(
                        1.f + __builtin_amdgcn_exp2f(-acc[0][nt][r]));
                    float c = sf * creg[nt][r] + u[nt][r];
                    float so = __builtin_amdgcn_rcpf(
                        1.f + __builtin_amdgcn_exp2f(-acc[1][nt][r]));
                    float th = 2.f * __builtin_amdgcn_rcpf(
                        1.f + __builtin_amdgcn_exp2f(-2.8853900817779268f * c)) - 1.f;
                    creg[nt][r] = c;
                    hv[r] = so * th;
                }
                // attention partial over this thread's 4 hidden units (f32 h)
                float p = hv[0] * Wa4.x + hv[1] * Wa4.y + hv[2] * Wa4.z + hv[3] * Wa4.w;
                p += __shfl_xor(p, 16);
                p += __shfl_xor(p, 32);  // sum over lq -> wave's 16 units
                if (lq == 0) part[(tt * 64 + nt * 16 + lr) * 8 + w] = p;
                if (s < 3) {             // h3 feeds nothing but attention
                    u32 p0, p1;
                    asm("v_cvt_pk_bf16_f32 %0, %1, %2" : "=v"(p0) : "v"(hv[0]), "v"(hv[1]));
                    asm("v_cvt_pk_bf16_f32 %0, %1, %2" : "=v"(p1) : "v"(hv[2]), "v"(hv[3]));
                    *(uint2*)&hS[(nt * 16 + lr) * 136 + grow0] = make_uint2(p0, p1);
                }
            }
        }
        if (s < 3) __syncthreads();      // new h visible
    }
    __syncthreads();                     // part visible
    if (t < 256) {
        int tt = t >> 6, node = t & 63;
        long gn = n0 + node;
        if (gn < N) {
            const float4* pp = (const float4*)&part[(tt * 64 + node) * 8];
            float4 a = pp[0], b = pp[1];
            scOut[gn * 4 + tt] = a.x + a.y + a.z + a.w + b.x + b.y + b.z + b.w;
        }
    }
}

// ---------------------------------------------------------------------------
__global__ __launch_bounds__(256) void final_kernel(
    const u16* __restrict__ jkB, const float* __restrict__ scores,
    const float* __restrict__ Wout, float* __restrict__ out, int N)
{
    __shared__ float feS[4][64];
    int t = threadIdx.x, l = t & 63, w = t >> 6;
    long n = (long)blockIdx.x * 4 + w;
    bool ok = (n < N);
    long nn = ok ? n : (long)(N - 1);
    float sc[4];
#pragma unroll
    for (int tt = 0; tt < 4; ++tt)
        sc[tt] = scores[nn * 4 + tt] + scores[(long)N * 4 + nn * 4 + tt];
    float m = fmaxf(fmaxf(sc[0], sc[1]), fmaxf(sc[2], sc[3]));
    float e0 = __expf(sc[0] - m), e1 = __expf(sc[1] - m);
    float e2 = __expf(sc[2] - m), e3 = __expf(sc[3] - m);
    float den = e0 + e1 + e2 + e3;
    float a0 = e0 / den, a1 = e1 / den, a2 = e2 / den, a3 = e3 / den;
    float fe = a0 * bf2f(jkB[nn * 64 + l]) + a1 * bf2f(jkB[((long)N + nn) * 64 + l]) +
               a2 * bf2f(jkB[((long)2 * N + nn) * 64 + l]) +
               a3 * bf2f(jkB[((long)3 * N + nn) * 64 + l]);
    feS[w][l] = fe;
    __syncthreads();
    float logit = 0.f;
    if (l < 40)
        for (int c = 0; c < 64; ++c) logit += feS[w][c] * Wout[l * 64 + c];
    float v = (l < 40) ? logit : -1e30f;
    for (int off = 32; off; off >>= 1) v = fmaxf(v, __shfl_xor(v, off));
    float ex = (l < 40) ? __expf(logit - v) : 0.f;
    for (int off = 32; off; off >>= 1) ex += __shfl_xor(ex, off);
    if (ok && l < 40) out[n * 40 + l] = logit - v - __logf(ex);
}

// ---------------------------------------------------------------------------
extern "C" void kernel_launch(void* const* d_in, const int* in_sizes, int n_in,
                              void* d_out, int out_size, void* d_ws, size_t ws_size,
                              hipStream_t stream)
{
    const float* x        = (const float*)d_in[0];
    const int*   eig      = (const int*)d_in[1];
    const float* eag      = (const float*)d_in[2];
    const int*   eilg     = (const int*)d_in[3];
    const float* ealg     = (const float*)d_in[4];
    const float* W_feat   = (const float*)d_in[5];
    const float* W_msg    = (const float*)d_in[6];
    const float* W_lg2g   = (const float*)d_in[7];
    const float* b_lg2g   = (const float*)d_in[8];
    const float* W_msg_l  = (const float*)d_in[9];
    const float* Wih_f    = (const float*)d_in[10];
    const float* Whh_f    = (const float*)d_in[11];
    const float* bih_f    = (const float*)d_in[12];
    const float* bhh_f    = (const float*)d_in[13];
    const float* Wih_b    = (const float*)d_in[14];
    const float* Whh_b    = (const float*)d_in[15];
    const float* bih_b    = (const float*)d_in[16];
    const float* bhh_b    = (const float*)d_in[17];
    const float* W_att    = (const float*)d_in[18];
    const float* W_out    = (const float*)d_in[20];

    int  N   = in_sizes[0] / 128;
    long Eg  = in_sizes[1] / 2;
    long Elg = in_sizes[3] / 2;

    char* wp = (char*)d_ws;
    auto alloc = [&](size_t bytes) -> char* {
        char* p = wp; wp += (bytes + 255) & ~(size_t)255; return p;
    };
    u16*   jkB    = (u16*)  alloc((size_t)4 * N * 64 * 2);
    u16*   mA     = (u16*)  alloc((size_t)Eg * 64 * 2);
    u16*   mB     = (u16*)  alloc((size_t)Eg * 64 * 2);
    float* scores = (float*)alloc((size_t)2 * N * 4 * 4);
    u16*   WhhB   = (u16*)  alloc((size_t)2 * 65536 * 2);
    u16*   WihB   = (u16*)  alloc((size_t)2 * 32768 * 2);
    float* BS     = (float*)alloc((size_t)2 * 512 * 4);
    u16*   WfeatB = (u16*)  alloc((size_t)8192 * 2);
    u16*   WmsgB  = (u16*)  alloc((size_t)9216 * 2);
    u16*   WmsgLB = (u16*)  alloc((size_t)18432 * 2);
    u16*   Wlg2gB = (u16*)  alloc((size_t)4096 * 2);
    u32*   off_g  = (u32*)  alloc((size_t)(N + 1) * 4);
    int*   list_g = (int*)  alloc((size_t)Eg * 4);
    u32*   off_lg = (u32*)  alloc((size_t)(Eg + 1) * 4);
    int*   list_lg= (int*)  alloc((size_t)Elg * 4);
    u32*   part   = (u32*)  alloc((size_t)1024 * 4);

    prep_w<<<928, 256, 0, stream>>>(Whh_f, Whh_b, Wih_f, Wih_b,
                                    bih_f, bhh_f, bih_b, bhh_b,
                                    W_feat, W_msg, W_msg_l, W_lg2g,
                                    WhhB, WihB, BS,
                                    WfeatB, WmsgB, WmsgLB, Wlg2gB);
    // ---- CSR build: both graphs ----
    hipMemsetAsync(off_g, 0, (size_t)(N + 1) * 4, stream);
    hipMemsetAsync(off_lg, 0, (size_t)(Eg + 1) * 4, stream);
    {
        long Emax = (Eg > Elg) ? Eg : Elg;
        count2<<<(int)((Emax + 255) / 256), 256, 0, stream>>>(
            eig + Eg, off_g, Eg, eilg + Elg, off_lg, Elg);
    }
    {
        int nb = (N + 1023) / 1024;
        scan1<<<nb, 256, 0, stream>>>(off_g, part, N);
        scan2<<<1, 1024, 0, stream>>>(part, nb, off_g + N);
        scan3<<<nb, 256, 0, stream>>>(off_g, part, N);
    }
    {
        int nb = (int)((Eg + 1023) / 1024);
        scan1<<<nb, 256, 0, stream>>>(off_lg, part, (int)Eg);
        scan2<<<1, 1024, 0, stream>>>(part, nb, off_lg + Eg);
        scan3<<<nb, 256, 0, stream>>>(off_lg, part, (int)Eg);
    }
    {
        long Emax = (Eg > Elg) ? Eg : Elg;
        fill2<<<(int)((Emax + 255) / 256), 256, 0, stream>>>(
            eig + Eg, off_g, list_g, Eg, eilg + Elg, off_lg, list_lg, Elg);
    }

    // jk0 = relu(x @ W_feat^T)
    rowgemm<128, true, false><<<(N + 63) / 64, 256, 0, stream>>>(
        x, WfeatB, nullptr, nullptr, jkB, N);
    // initial msgs -> mA
    edge_msg_init2<<<(int)((Eg + 127) / 128), 512, 0, stream>>>(
        jkB, eig, eag, WmsgB, mA, Eg);
    // jk1 = gather(mA) @ W_lg2g^T + deg*b   (fused)
    gather_gw<<<(N + 3) / 4, 256, 0, stream>>>(
        mA, list_g, off_g, Wlg2gB, b_lg2g, 1, jkB + (size_t)N * 64, N);
    // ---- linegraph layer 0: mA -> mB ----
    zero_fill<<<(int)((Eg * 8 + 255) / 256), 256, 0, stream>>>(off_lg, mB, Eg);
    edge_msg_lg2<<<(int)((Elg + 127) / 128), 512, 0, stream>>>(
        mA, eilg, ealg, WmsgLB, list_lg, mB, Elg);
    gather_gw<<<(N + 3) / 4, 256, 0, stream>>>(
        mB, list_g, off_g, Wlg2gB, b_lg2g, 0, jkB + (size_t)2 * N * 64, N);
    // ---- linegraph layer 1: mB -> mA ----
    zero_fill<<<(int)((Eg * 8 + 255) / 256), 256, 0, stream>>>(off_lg, mA, Eg);
    edge_msg_lg2<<<(int)((Elg + 127) / 128), 512, 0, stream>>>(
        mB, eilg, ealg, WmsgLB + 9216, list_lg, mA, Elg);
    gather_gw<<<(N + 3) / 4, 256, 0, stream>>>(
        mA, list_g, off_g, Wlg2gB, b_lg2g, 0, jkB + (size_t)3 * N * 64, N);
    // ---- JK bidirectional LSTM ----
    {
        int ntiles = (N + 63) / 64;
        lstm3<<<dim3(ntiles, 2), 512, 0, stream>>>(
            jkB, WhhB, WihB, BS, W_att, scores, N);
    }
    final_kernel<<<(N + 3) / 4, 256, 0, stream>>>(
        jkB, scores, W_out, (float*)d_out, N);
}

// Round 11
// 1002.332 us; speedup vs baseline: 1.0395x; 1.0395x over previous
//
#include <hip/hip_runtime.h>

typedef unsigned short u16;
typedef unsigned int u32;
typedef __attribute__((ext_vector_type(8))) short bf16x8;
typedef __attribute__((ext_vector_type(4))) float f32x4;

#define MFMA(a, b, c) __builtin_amdgcn_mfma_f32_16x16x32_bf16(a, b, c, 0, 0, 0)

__device__ __forceinline__ u16 f2bf(float x) {
    union { float f; u32 u; } v; v.f = x;
    u32 r = (v.u + 0x7FFFu + ((v.u >> 16) & 1u)) >> 16;
    return (u16)r;
}
__device__ __forceinline__ float bf2f(u16 b) {
    union { u32 u; float f; } v; v.u = ((u32)b) << 16;
    return v.f;
}
__device__ __forceinline__ void casAddPair(u32* w, float lo, float hi) {
    u32 old = *w, assumed;
    do {
        assumed = old;
        u32 des = (u32)f2bf(bf2f((u16)(assumed & 0xFFFFu)) + lo) |
                  ((u32)f2bf(bf2f((u16)(assumed >> 16)) + hi) << 16);
        if (des == assumed) break;
        old = atomicCAS(w, assumed, des);
    } while (old != assumed);
}

// ---------------------------------------------------------------------------
// prep: convert LSTM weights to bf16 (gate rows pre-scaled by log2e, g-gate by
// 2*log2e for native v_exp_f32), combine biases, and pre-convert the other
// weight matrices to bf16 so per-block staging is pure vector copies.
__global__ __launch_bounds__(256) void prep_w(
    const float* __restrict__ Whh_f, const float* __restrict__ Whh_b,
    const float* __restrict__ Wih_f, const float* __restrict__ Wih_b,
    const float* __restrict__ bih_f, const float* __restrict__ bhh_f,
    const float* __restrict__ bih_b, const float* __restrict__ bhh_b,
    const float* __restrict__ W_feat, const float* __restrict__ W_msg,
    const float* __restrict__ W_msg_l, const float* __restrict__ W_lg2g,
    u16* __restrict__ WhhB, u16* __restrict__ WihB, float* __restrict__ BS,
    u16* __restrict__ WfeatB, u16* __restrict__ WmsgB,
    u16* __restrict__ WmsgLB, u16* __restrict__ Wlg2gB)
{
    const float L2E = 1.4426950408889634f;
    int i = blockIdx.x * 256 + threadIdx.x;
    if (i < 131072) {
        int d = i >> 16, r = i & 65535;
        float s = (((r >> 14) & 3) == 2) ? 2.f * L2E : L2E;
        WhhB[i] = f2bf(s * (d ? Whh_b[r] : Whh_f[r]));
    } else if (i < 196608) {
        int i2 = i - 131072; int d = i2 >> 15, r = i2 & 32767;
        float s = (((r >> 13) & 3) == 2) ? 2.f * L2E : L2E;
        WihB[i2] = f2bf(s * (d ? Wih_b[r] : Wih_f[r]));
    } else if (i < 197632) {
        int i3 = i - 196608; int d = i3 >> 9, g = i3 & 511;
        float s = (((g >> 7) & 3) == 2) ? 2.f * L2E : L2E;
        BS[i3] = s * (d ? (bih_b[g] + bhh_b[g]) : (bih_f[g] + bhh_f[g]));
    } else if (i < 205824) {
        int j = i - 197632; WfeatB[j] = f2bf(W_feat[j]);
    } else if (i < 215040) {
        int j = i - 205824; WmsgB[j] = f2bf(W_msg[j]);
    } else if (i < 233472) {
        int j = i - 215040; WmsgLB[j] = f2bf(W_msg_l[j]);
    } else if (i < 237568) {
        int j = i - 233472; Wlg2gB[j] = f2bf(W_lg2g[j]);
    }
}

// ---------------------------------------------------------------------------
// CSR build — both graphs counted / filled in single launches.
__global__ __launch_bounds__(256) void count2(
    const int* __restrict__ dg, u32* __restrict__ cg, long Eg,
    const int* __restrict__ dl, u32* __restrict__ cl, long El)
{
    long i = (long)blockIdx.x * 256 + threadIdx.x;
    if (i < Eg) atomicAdd(&cg[dg[i]], 1u);
    if (i < El) atomicAdd(&cl[dl[i]], 1u);
}

__global__ __launch_bounds__(256) void fill2(
    const int* __restrict__ dg, u32* __restrict__ og, int* __restrict__ lg_,
    long Eg,
    const int* __restrict__ dl, u32* __restrict__ ol, int* __restrict__ ll,
    long El)
{
    long i = (long)blockIdx.x * 256 + threadIdx.x;
    if (i < Eg) { u32 p = atomicAdd(&og[dg[i]], 1u); lg_[p] = (int)i; }
    if (i < El) { u32 p = atomicAdd(&ol[dl[i]], 1u); ll[p] = (int)i; }
}

__global__ __launch_bounds__(256) void scan1(const u32* __restrict__ a,
                                             u32* __restrict__ part, int n)
{
    __shared__ u32 ts[256];
    int b = blockIdx.x, t = threadIdx.x;
    long i0 = (long)b * 1024 + t * 4;
    u32 s = 0;
#pragma unroll
    for (int k = 0; k < 4; ++k) { long i = i0 + k; if (i < n) s += a[i]; }
    ts[t] = s; __syncthreads();
    for (int off = 1; off < 256; off <<= 1) {
        u32 x = (t >= off) ? ts[t - off] : 0u;
        __syncthreads(); ts[t] += x; __syncthreads();
    }
    if (t == 255) part[b] = ts[255];
}

__global__ __launch_bounds__(1024) void scan2(u32* __restrict__ part, int nb,
                                              u32* __restrict__ total_out)
{
    __shared__ u32 ts[1024];
    int t = threadIdx.x;
    u32 v = (t < nb) ? part[t] : 0u;
    ts[t] = v; __syncthreads();
    for (int off = 1; off < 1024; off <<= 1) {
        u32 x = (t >= off) ? ts[t - off] : 0u;
        __syncthreads(); ts[t] += x; __syncthreads();
    }
    if (t < nb) part[t] = ts[t] - v;
    if (t == 1023 && total_out) *total_out = ts[1023];
}

__global__ __launch_bounds__(256) void scan3(u32* __restrict__ a,
                                             const u32* __restrict__ part, int n)
{
    __shared__ u32 ts[256];
    int b = blockIdx.x, t = threadIdx.x;
    long i0 = (long)b * 1024 + t * 4;
    u32 v[4]; u32 s = 0;
#pragma unroll
    for (int k = 0; k < 4; ++k) { long i = i0 + k; v[k] = (i < n) ? a[i] : 0u; s += v[k]; }
    ts[t] = s; __syncthreads();
    for (int off = 1; off < 256; off <<= 1) {
        u32 x = (t >= off) ? ts[t - off] : 0u;
        __syncthreads(); ts[t] += x; __syncthreads();
    }
    u32 run = part[b] + ts[t] - s;
#pragma unroll
    for (int k = 0; k < 4; ++k) {
        long i = i0 + k;
        if (i < n) { u32 x = v[k]; a[i] = run; run += x; }
    }
}

// ---------------------------------------------------------------------------
__global__ __launch_bounds__(256) void zero_fill(const u32* __restrict__ offc,
                                                 u16* __restrict__ outb, long NB)
{
    long idx = (long)blockIdx.x * 256 + threadIdx.x;
    long n = idx >> 3; int q = (int)(idx & 7);
    if (n >= NB) return;
    u32 s = n ? offc[n - 1] : 0u;
    u32 e = offc[n];
    bool need = (s == e) || ((s >> 7) != ((e - 1) >> 7));
    if (need) *(uint4*)(outb + n * 64 + q * 8) = make_uint4(0, 0, 0, 0);
}

// ---------------------------------------------------------------------------
// rowgemm: outb[M x 64] (bf16) = act(in[M x K] @ W[64 x K]^T (+ bias*scale))
template <int K, bool RELU, bool INBF16>
__global__ __launch_bounds__(256) void rowgemm(
    const void* __restrict__ in, const u16* __restrict__ W,
    const float* __restrict__ bias, const float* __restrict__ bias_scale,
    u16* __restrict__ outb, int M)
{
    constexpr int KP = K + 8;
    constexpr int K8 = K / 8;
    __shared__ u16 inS[64 * KP];
    __shared__ u16 WS[64 * KP];
    int t = threadIdx.x;
    long rb = (long)blockIdx.x * 64;
    for (int i = t; i < 64 * K8; i += 256) {
        int c = i / K8, q = i - c * K8;
        *(uint4*)&WS[c * KP + q * 8] = *(const uint4*)&W[c * K + q * 8];
    }
    if (INBF16) {
        const u16* inb = (const u16*)in;
        for (int i = t; i < 64 * K8; i += 256) {
            int r = i / K8, q = i - r * K8;
            long gr = rb + r;
            uint4 v = make_uint4(0, 0, 0, 0);
            if (gr < M) v = *(const uint4*)&inb[gr * (long)K + q * 8];
            *(uint4*)&inS[r * KP + q * 8] = v;
        }
    } else {
        const float* inf = (const float*)in;
        for (int i = t; i < 64 * K; i += 256) {
            int r = i / K, k = i - r * K;
            long gr = rb + r;
            inS[r * KP + k] = (gr < M) ? f2bf(inf[gr * (long)K + k]) : (u16)0;
        }
    }
    __syncthreads();
    int l = t & 63, w = t >> 6, lr = l & 15, lq = l >> 4;
    f32x4 acc[4];
#pragma unroll
    for (int i = 0; i < 4; ++i) acc[i] = (f32x4){0.f, 0.f, 0.f, 0.f};
#pragma unroll
    for (int kc = 0; kc < K; kc += 32) {
        bf16x8 a = *(const bf16x8*)&inS[(w * 16 + lr) * KP + kc + lq * 8];
#pragma unroll
        for (int ct = 0; ct < 4; ++ct) {
            bf16x8 b = *(const bf16x8*)&WS[(ct * 16 + lr) * KP + kc + lq * 8];
            acc[ct] = MFMA(a, b, acc[ct]);
        }
    }
#pragma unroll
    for (int ct = 0; ct < 4; ++ct)
#pragma unroll
        for (int r = 0; r < 4; ++r) {
            long gr = rb + w * 16 + lq * 4 + r;
            if (gr < M) {
                int c = ct * 16 + lr;
                float v = acc[ct][r];
                if (bias) v += bias[c] * (bias_scale ? bias_scale[gr] : 1.f);
                if (RELU) v = fmaxf(v, 0.f);
                outb[gr * 64 + c] = f2bf(v);
            }
        }
}

// ---------------------------------------------------------------------------
// edge_msg_init2: direct-gather A-fragments; W pre-converted bf16, attr f32.
__global__ __launch_bounds__(512, 4) void edge_msg_init2(
    const u16* __restrict__ feat, const int* __restrict__ ei,
    const float* __restrict__ attr, const u16* __restrict__ W,
    u16* __restrict__ outb, long E)
{
    __shared__ u16 WS[64 * 168];
    __shared__ u16 eds[128 * 64];
    int t = threadIdx.x;
    long eb = (long)blockIdx.x * 128;
    int w = t >> 6, l = t & 63, lr = l & 15, lq = l >> 4;
    long e = eb + w * 16 + lr;
    long ec = (e < E) ? e : (E - 1);
    int src = ei[ec], dst = ei[E + ec];
    bf16x8 A[5];
    {
        const uint4* sp = (const uint4*)(feat + (long)src * 64);
        const uint4* dp = (const uint4*)(feat + (long)dst * 64);
        *(uint4*)&A[0] = sp[lq];
        *(uint4*)&A[1] = sp[4 + lq];
        *(uint4*)&A[2] = dp[lq];
        *(uint4*)&A[3] = dp[4 + lq];
        uint4 pv = make_uint4(0, 0, 0, 0);
        if (lq < 2) {
            const float4* ap = (const float4*)(attr + ec * 16) + lq * 2;
            float4 b0 = ap[0], b1 = ap[1];
            pv.x = (u32)f2bf(b0.x) | ((u32)f2bf(b0.y) << 16);
            pv.y = (u32)f2bf(b0.z) | ((u32)f2bf(b0.w) << 16);
            pv.z = (u32)f2bf(b1.x) | ((u32)f2bf(b1.y) << 16);
            pv.w = (u32)f2bf(b1.z) | ((u32)f2bf(b1.w) << 16);
        }
        *(uint4*)&A[4] = pv;
    }
    for (int i = t; i < 1152; i += 512) {                 // 64*144/8
        int c = i / 18, q = i - c * 18;
        *(uint4*)&WS[c * 168 + q * 8] = *(const uint4*)&W[c * 144 + q * 8];
    }
    if (t < 192) {                                        // 64*24/8 zero pad
        int c = t / 3, q = t - c * 3;
        *(uint4*)&WS[c * 168 + 144 + q * 8] = make_uint4(0, 0, 0, 0);
    }
    __syncthreads();
    f32x4 acc[4];
#pragma unroll
    for (int ct = 0; ct < 4; ++ct) acc[ct] = (f32x4){0.f, 0.f, 0.f, 0.f};
#pragma unroll
    for (int kc = 0; kc < 5; ++kc) {
#pragma unroll
        for (int ct = 0; ct < 4; ++ct) {
            bf16x8 b = *(const bf16x8*)&WS[(ct * 16 + lr) * 168 + kc * 32 + lq * 8];
            acc[ct] = MFMA(A[kc], b, acc[ct]);
        }
    }
#pragma unroll
    for (int ct = 0; ct < 4; ++ct)
#pragma unroll
        for (int r = 0; r < 4; ++r) {
            int row = w * 16 + lq * 4 + r;
            int col = ct * 16 + lr;
            eds[row * 64 + col] = f2bf(fmaxf(acc[ct][r], 0.f));
        }
    __syncthreads();
    for (int j = t; j < 1024; j += 512) {
        int le = j >> 3, q = j & 7;
        long e2 = eb + le;
        if (e2 < E)
            *(uint4*)(outb + e2 * 64 + q * 8) = *(const uint4*)&eds[le * 64 + q * 8];
    }
}

// ---------------------------------------------------------------------------
// edge_msg_lg2: dst-sorted (CSR) order, segmented reduction epilogue.
// REVERTED to r9's staged-index form: t<128 stages list/ei once into LDS
// (r10's per-thread direct loads 4x'd the random ei request traffic and
// regressed the pipeline ~47 us).
__global__ __launch_bounds__(512, 4) void edge_msg_lg2(
    const u16* __restrict__ feat, const int* __restrict__ ei,
    const float* __restrict__ attr, const u16* __restrict__ W,
    const int* __restrict__ list, u16* __restrict__ outb, long E)
{
    __shared__ u16 WS[64 * 168];
    __shared__ u16 eds[128 * 64];
    __shared__ int dstS[128];
    __shared__ int idS[128];
    __shared__ int srcS[128];
    __shared__ int dprevS, dnextS;
    int t = threadIdx.x;
    long pb = (long)blockIdx.x * 128;
    for (int i = t; i < 1152; i += 512) {
        int c = i / 18, q = i - c * 18;
        *(uint4*)&WS[c * 168 + q * 8] = *(const uint4*)&W[c * 144 + q * 8];
    }
    if (t < 192) {
        int c = t / 3, q = t - c * 3;
        *(uint4*)&WS[c * 168 + 144 + q * 8] = make_uint4(0, 0, 0, 0);
    }
    if (t < 128) {
        long p = pb + t;
        int id = (p < E) ? list[p] : -1;
        idS[t] = id;
        srcS[t] = (id >= 0) ? ei[id] : 0;
        dstS[t] = (id >= 0) ? ei[E + id] : -1;
    } else if (t == 128) {
        dprevS = (pb > 0) ? ei[E + list[pb - 1]] : -2;
    } else if (t == 129) {
        dnextS = (pb + 128 < E) ? ei[E + list[pb + 128]] : -2;
    }
    __syncthreads();
    int w = t >> 6, l = t & 63, lr = l & 15, lq = l >> 4;
    int el = w * 16 + lr;
    int id = idS[el];
    long idc = (id >= 0) ? (long)id : 0;
    int src = srcS[el];
    int dst = (dstS[el] >= 0) ? dstS[el] : 0;
    bf16x8 A[5];
    {
        const uint4* sp = (const uint4*)(feat + (long)src * 64);
        const uint4* dp = (const uint4*)(feat + (long)dst * 64);
        *(uint4*)&A[0] = sp[lq];
        *(uint4*)&A[1] = sp[4 + lq];
        *(uint4*)&A[2] = dp[lq];
        *(uint4*)&A[3] = dp[4 + lq];
        uint4 pv = make_uint4(0, 0, 0, 0);
        if (lq < 2) {
            const float4* ap = (const float4*)(attr + idc * 16) + lq * 2;
            float4 b0 = ap[0], b1 = ap[1];
            pv.x = (u32)f2bf(b0.x) | ((u32)f2bf(b0.y) << 16);
            pv.y = (u32)f2bf(b0.z) | ((u32)f2bf(b0.w) << 16);
            pv.z = (u32)f2bf(b1.x) | ((u32)f2bf(b1.y) << 16);
            pv.w = (u32)f2bf(b1.z) | ((u32)f2bf(b1.w) << 16);
        }
        *(uint4*)&A[4] = pv;
    }
    f32x4 acc[4];
#pragma unroll
    for (int ct = 0; ct < 4; ++ct) acc[ct] = (f32x4){0.f, 0.f, 0.f, 0.f};
#pragma unroll
    for (int kc = 0; kc < 5; ++kc) {
#pragma unroll
        for (int ct = 0; ct < 4; ++ct) {
            bf16x8 b = *(const bf16x8*)&WS[(ct * 16 + lr) * 168 + kc * 32 + lq * 8];
            acc[ct] = MFMA(A[kc], b, acc[ct]);
        }
    }
#pragma unroll
    for (int ct = 0; ct < 4; ++ct)
#pragma unroll
        for (int r = 0; r < 4; ++r) {
            int row = w * 16 + lq * 4 + r;
            int col = ct * 16 + lr;
            eds[row * 64 + col] = f2bf(fmaxf(acc[ct][r], 0.f));
        }
    __syncthreads();
    for (int j = t; j < 4096; j += 512) {
        int le = j >> 5, wd = j & 31;
        int d = dstS[le];
        if (d < 0) continue;
        if (le > 0 && dstS[le - 1] == d) continue;
        float lo = 0.f, hi = 0.f;
        int le2 = le;
        do {
            u32 pair = *(const u32*)&eds[le2 * 64 + wd * 2];
            lo += bf2f((u16)(pair & 0xFFFFu));
            hi += bf2f((u16)(pair >> 16));
            ++le2;
        } while (le2 < 128 && dstS[le2] == d);
        bool bprev = (le == 0 && dprevS == d);
        bool bnext = (le2 == 128 && dnextS == d);
        u32* dw = (u32*)(outb + (long)d * 64 + wd * 2);
        if (bprev || bnext) {
            casAddPair(dw, lo, hi);
        } else {
            *dw = (u32)f2bf(lo) | ((u32)f2bf(hi) << 16);
        }
    }
}

// ---------------------------------------------------------------------------
// gather_gw: FUSED gather + 64x64 linear. One wave per node (halves do
// even/odd list positions); 8-deep manual unroll keeps 8 independent L3
// line-reads in flight per half-wave. f32 agg -> LDS -> 64-lane matvec vs
// transposed W (pad 66).
__global__ __launch_bounds__(256) void gather_gw(
    const u16* __restrict__ m, const int* __restrict__ list,
    const u32* __restrict__ offc, const u16* __restrict__ Wg,
    const float* __restrict__ bias, int useDeg,
    u16* __restrict__ outb, int N)
{
    __shared__ u16 WS[64 * 66];       // transposed: WS[k*66+r] = W[r][k]
    __shared__ float aggS[4][64];
    __shared__ float degS[4];
    int t = threadIdx.x;
    for (int i = t; i < 4096; i += 256) {
        int r = i >> 6, k = i & 63;
        WS[k * 66 + r] = Wg[i];
    }
    int wv = t >> 6, l = t & 63, c = l & 31, half = l >> 5;
    long n = (long)blockIdx.x * 4 + wv;
    long nn = (n < N) ? n : (long)(N - 1);
    u32 start = nn ? offc[nn - 1] : 0u;
    u32 end = offc[nn];
    float s0 = 0.f, s1 = 0.f, s2 = 0.f, s3 = 0.f;
    float s4 = 0.f, s5 = 0.f, s6 = 0.f, s7 = 0.f;
    float t0 = 0.f, t1 = 0.f, t2 = 0.f, t3 = 0.f;
    float t4 = 0.f, t5 = 0.f, t6 = 0.f, t7 = 0.f;
    u32 i = start + half;
    for (; i + 14 < end; i += 16) {   // 8 stride-2 elems per half-wave
        int e0 = list[i],      e1 = list[i + 2],  e2 = list[i + 4],  e3 = list[i + 6];
        int e4 = list[i + 8],  e5 = list[i + 10], e6 = list[i + 12], e7 = list[i + 14];
        u32 p0 = *(const u32*)&m[(long)e0 * 64 + c * 2];
        u32 p1 = *(const u32*)&m[(long)e1 * 64 + c * 2];
        u32 p2 = *(const u32*)&m[(long)e2 * 64 + c * 2];
        u32 p3 = *(const u32*)&m[(long)e3 * 64 + c * 2];
        u32 p4 = *(const u32*)&m[(long)e4 * 64 + c * 2];
        u32 p5 = *(const u32*)&m[(long)e5 * 64 + c * 2];
        u32 p6 = *(const u32*)&m[(long)e6 * 64 + c * 2];
        u32 p7 = *(const u32*)&m[(long)e7 * 64 + c * 2];
        s0 += bf2f((u16)(p0 & 0xFFFFu)); t0 += bf2f((u16)(p0 >> 16));
        s1 += bf2f((u16)(p1 & 0xFFFFu)); t1 += bf2f((u16)(p1 >> 16));
        s2 += bf2f((u16)(p2 & 0xFFFFu)); t2 += bf2f((u16)(p2 >> 16));
        s3 += bf2f((u16)(p3 & 0xFFFFu)); t3 += bf2f((u16)(p3 >> 16));
        s4 += bf2f((u16)(p4 & 0xFFFFu)); t4 += bf2f((u16)(p4 >> 16));
        s5 += bf2f((u16)(p5 & 0xFFFFu)); t5 += bf2f((u16)(p5 >> 16));
        s6 += bf2f((u16)(p6 & 0xFFFFu)); t6 += bf2f((u16)(p6 >> 16));
        s7 += bf2f((u16)(p7 & 0xFFFFu)); t7 += bf2f((u16)(p7 >> 16));
    }
    for (; i + 6 < end; i += 8) {     // 4-deep tail
        int e0 = list[i], e1 = list[i + 2], e2 = list[i + 4], e3 = list[i + 6];
        u32 p0 = *(const u32*)&m[(long)e0 * 64 + c * 2];
        u32 p1 = *(const u32*)&m[(long)e1 * 64 + c * 2];
        u32 p2 = *(const u32*)&m[(long)e2 * 64 + c * 2];
        u32 p3 = *(const u32*)&m[(long)e3 * 64 + c * 2];
        s0 += bf2f((u16)(p0 & 0xFFFFu)); t0 += bf2f((u16)(p0 >> 16));
        s1 += bf2f((u16)(p1 & 0xFFFFu)); t1 += bf2f((u16)(p1 >> 16));
        s2 += bf2f((u16)(p2 & 0xFFFFu)); t2 += bf2f((u16)(p2 >> 16));
        s3 += bf2f((u16)(p3 & 0xFFFFu)); t3 += bf2f((u16)(p3 >> 16));
    }
    for (; i < end; i += 2) {
        int e = list[i];
        u32 pair = *(const u32*)&m[(long)e * 64 + c * 2];
        s0 += bf2f((u16)(pair & 0xFFFFu));
        t0 += bf2f((u16)(pair >> 16));
    }
    float slo = ((s0 + s1) + (s2 + s3)) + ((s4 + s5) + (s6 + s7));
    float shi = ((t0 + t1) + (t2 + t3)) + ((t4 + t5) + (t6 + t7));
    slo += __shfl_xor(slo, 32);
    shi += __shfl_xor(shi, 32);
    if (half == 0) { aggS[wv][c * 2] = slo; aggS[wv][c * 2 + 1] = shi; }
    if (l == 0) degS[wv] = (float)(end - start);
    __syncthreads();
    float acc = 0.f;
#pragma unroll 8
    for (int k = 0; k < 64; ++k)
        acc += aggS[wv][k] * bf2f(WS[k * 66 + l]);
    float scale = useDeg ? degS[wv] : 1.f;
    acc += bias[l] * scale;
    if (n < N) outb[n * 64 + l] = f2bf(acc);
}

// ---------------------------------------------------------------------------
// lstm3: bidirectional JK-LSTM, 64 nodes/tile — round-2's proven all-LDS
// dataflow (159 us, VGPR 108, no spill). Structurally done: Wh (64 regs) +
// acc AGPRs put total regs ~172 -> hard 2 waves/SIMD; Whh (128 KB/dir)
// cannot be LDS-resident, so 4 waves/SIMD without spill is infeasible.
__global__ __launch_bounds__(512, 2) void lstm3(
    const u16* __restrict__ jkB, const u16* __restrict__ WhhB,
    const u16* __restrict__ WihB, const float* __restrict__ BS,
    const float* __restrict__ Watt, float* __restrict__ scores,
    int N)
{
    __shared__ u16 hS[64 * 136];         // 17408 B
    __shared__ u16 xS[4][64 * 72];       // 36864 B
    __shared__ u16 WiS[512 * 72];        // 73728 B (padded stride 72)
    __shared__ float bsS[512];           //  2048 B
    __shared__ float part[4 * 64 * 8];   //  8192 B   total 138240 B
    int t = threadIdx.x;
    int dir = blockIdx.y;
    int w = t >> 6, l = t & 63, lr = l & 15, lq = l >> 4;
    const u16* WhhD = WhhB + (long)dir * 65536;
    const u16* WihD = WihB + (long)dir * 32768;
    long n0 = (long)blockIdx.x * 64;

    // stage x for all 4 JK steps
    {
        int n = t >> 3, j = t & 7;
        long gn = n0 + n;
#pragma unroll
        for (int k = 0; k < 4; ++k) {
            uint4 v = make_uint4(0, 0, 0, 0);
            if (gn < N) v = *(const uint4*)&jkB[((long)k * N + gn) * 64 + j * 8];
            *(uint4*)&xS[k][n * 72 + j * 8] = v;
        }
    }
    // stage Wi (512 gate-rows x 64, padded to 72) and bias
#pragma unroll
    for (int i = t; i < 4096; i += 512) {
        int g = i >> 3, q = i & 7;
        *(uint4*)&WiS[g * 72 + q * 8] = *(const uint4*)&WihD[g * 64 + q * 8];
    }
    bsS[t] = BS[dir * 512 + t];

    int grow0 = w * 16 + lq * 4;         // this thread's first hidden unit
    bf16x8 Wh[4][4];
#pragma unroll
    for (int ty = 0; ty < 4; ++ty) {
        int g = ty * 128 + w * 16 + lr;
#pragma unroll
        for (int kc = 0; kc < 4; ++kc)
            Wh[ty][kc] = *(const bf16x8*)&WhhD[g * 128 + kc * 32 + lq * 8];
    }
    float4 Wa4 = *(const float4*)&Watt[dir * 128 + grow0];
    float* scOut = scores + (long)dir * N * 4;

    float creg[4][4] = {};
    __syncthreads();                     // xS / WiS / bsS visible

#pragma unroll 1
    for (int s = 0; s < 4; ++s) {
        int tt = dir ? (3 - s) : s;
        float u[4][4];
        // ---------------- pass A: gates i (0) and g (2) -> u ----------------
        {
            f32x4 acc[2][4];
            f32x4 bi = *(const f32x4*)&bsS[grow0];
            f32x4 bg = *(const f32x4*)&bsS[256 + grow0];
#pragma unroll
            for (int nt = 0; nt < 4; ++nt) { acc[0][nt] = bi; acc[1][nt] = bg; }
            if (s) {
#pragma unroll
                for (int kc = 0; kc < 4; ++kc) {
                    bf16x8 a[4];
#pragma unroll
                    for (int nt = 0; nt < 4; ++nt)
                        a[nt] = *(const bf16x8*)&hS[(nt * 16 + lr) * 136 + kc * 32 + lq * 8];
#pragma unroll
                    for (int nt = 0; nt < 4; ++nt) {
                        acc[0][nt] = MFMA(Wh[0][kc], a[nt], acc[0][nt]);
                        acc[1][nt] = MFMA(Wh[2][kc], a[nt], acc[1][nt]);
                    }
                }
            }
#pragma unroll
            for (int kc = 0; kc < 2; ++kc) {
                bf16x8 wi = *(const bf16x8*)&WiS[(w * 16 + lr) * 72 + kc * 32 + lq * 8];
                bf16x8 wg = *(const bf16x8*)&WiS[(256 + w * 16 + lr) * 72 + kc * 32 + lq * 8];
                bf16x8 a[4];
#pragma unroll
                for (int nt = 0; nt < 4; ++nt)
                    a[nt] = *(const bf16x8*)&xS[tt][(nt * 16 + lr) * 72 + kc * 32 + lq * 8];
#pragma unroll
                for (int nt = 0; nt < 4; ++nt) {
                    acc[0][nt] = MFMA(wi, a[nt], acc[0][nt]);
                    acc[1][nt] = MFMA(wg, a[nt], acc[1][nt]);
                }
            }
#pragma unroll
            for (int nt = 0; nt < 4; ++nt)
#pragma unroll
                for (int r = 0; r < 4; ++r) {
                    float si = __builtin_amdgcn_rcpf(
                        1.f + __builtin_amdgcn_exp2f(-acc[0][nt][r]));
                    float tg = 2.f * __builtin_amdgcn_rcpf(
                        1.f + __builtin_amdgcn_exp2f(-acc[1][nt][r])) - 1.f;
                    u[nt][r] = si * tg;
                }
        }
        // ---------------- pass B: gates f (1) and o (3) -> c, h -------------
        {
            f32x4 acc[2][4];
            f32x4 bf = *(const f32x4*)&bsS[128 + grow0];
            f32x4 bo = *(const f32x4*)&bsS[384 + grow0];
#pragma unroll
            for (int nt = 0; nt < 4; ++nt) { acc[0][nt] = bf; acc[1][nt] = bo; }
            if (s) {
#pragma unroll
                for (int kc = 0; kc < 4; ++kc) {
                    bf16x8 a[4];
#pragma unroll
                    for (int nt = 0; nt < 4; ++nt)
                        a[nt] = *(const bf16x8*)&hS[(nt * 16 + lr) * 136 + kc * 32 + lq * 8];
#pragma unroll
                    for (int nt = 0; nt < 4; ++nt) {
                        acc[0][nt] = MFMA(Wh[1][kc], a[nt], acc[0][nt]);
                        acc[1][nt] = MFMA(Wh[3][kc], a[nt], acc[1][nt]);
                    }
                }
            }
#pragma unroll
            for (int kc = 0; kc < 2; ++kc) {
                bf16x8 wf = *(const bf16x8*)&WiS[(128 + w * 16 + lr) * 72 + kc * 32 + lq * 8];
                bf16x8 wo = *(const bf16x8*)&WiS[(384 + w * 16 + lr) * 72 + kc * 32 + lq * 8];
                bf16x8 a[4];
#pragma unroll
                for (int nt = 0; nt < 4; ++nt)
                    a[nt] = *(const bf16x8*)&xS[tt][(nt * 16 + lr) * 72 + kc * 32 + lq * 8];
#pragma unroll
                for (int nt = 0; nt < 4; ++nt) {
                    acc[0][nt] = MFMA(wf, a[nt], acc[0][nt]);
                    acc[1][nt] = MFMA(wo, a[nt], acc[1][nt]);
                }
            }
            if (s) __syncthreads();      // all hS reads (A+B) done before overwrite
#pragma unroll
            for (int nt = 0; nt < 4; ++nt) {
                float hv[4];
#pragma unroll
                for (int r = 0; r < 4; ++r) {
                    float sf = __builtin_amdgcn_rcpf(
                        1.f + __builtin_amdgcn_exp2f(-acc[0][nt][r]));
                    float c = sf * creg[nt][r] + u[nt][r];
                    float so = __builtin_amdgcn_rcpf(
                        1.f + __builtin_amdgcn_exp2f(-acc[1][nt][r]));
                    float th = 2.f * __builtin_amdgcn_rcpf(
                        1.f + __builtin_amdgcn_exp2f(-2.8853900817779268f * c)) - 1.f;
                    creg[nt][r] = c;
                    hv[r] = so * th;
                }
                // attention partial over this thread's 4 hidden units (f32 h)
                float p = hv[0] * Wa4.x + hv[1] * Wa4.y + hv[2] * Wa4.z + hv[3] * Wa4.w;
                p += __shfl_xor(p, 16);
                p += __shfl_xor(p, 32);  // sum over lq -> wave's 16 units
                if (lq == 0) part[(tt * 64 + nt * 16 + lr) * 8 + w] = p;
                if (s < 3) {             // h3 feeds nothing but attention
                    u32 p0, p1;
                    asm("v_cvt_pk_bf16_f32 %0, %1, %2" : "=v"(p0) : "v"(hv[0]), "v"(hv[1]));
                    asm("v_cvt_pk_bf16_f32 %0, %1, %2" : "=v"(p1) : "v"(hv[2]), "v"(hv[3]));
                    *(uint2*)&hS[(nt * 16 + lr) * 136 + grow0] = make_uint2(p0, p1);
                }
            }
        }
        if (s < 3) __syncthreads();      // new h visible
    }
    __syncthreads();                     // part visible
    if (t < 256) {
        int tt = t >> 6, node = t & 63;
        long gn = n0 + node;
        if (gn < N) {
            const float4* pp = (const float4*)&part[(tt * 64 + node) * 8];
            float4 a = pp[0], b = pp[1];
            scOut[gn * 4 + tt] = a.x + a.y + a.z + a.w + b.x + b.y + b.z + b.w;
        }
    }
}

// ---------------------------------------------------------------------------
__global__ __launch_bounds__(256) void final_kernel(
    const u16* __restrict__ jkB, const float* __restrict__ scores,
    const float* __restrict__ Wout, float* __restrict__ out, int N)
{
    __shared__ float feS[4][64];
    int t = threadIdx.x, l = t & 63, w = t >> 6;
    long n = (long)blockIdx.x * 4 + w;
    bool ok = (n < N);
    long nn = ok ? n : (long)(N - 1);
    float sc[4];
#pragma unroll
    for (int tt = 0; tt < 4; ++tt)
        sc[tt] = scores[nn * 4 + tt] + scores[(long)N * 4 + nn * 4 + tt];
    float m = fmaxf(fmaxf(sc[0], sc[1]), fmaxf(sc[2], sc[3]));
    float e0 = __expf(sc[0] - m), e1 = __expf(sc[1] - m);
    float e2 = __expf(sc[2] - m), e3 = __expf(sc[3] - m);
    float den = e0 + e1 + e2 + e3;
    float a0 = e0 / den, a1 = e1 / den, a2 = e2 / den, a3 = e3 / den;
    float fe = a0 * bf2f(jkB[nn * 64 + l]) + a1 * bf2f(jkB[((long)N + nn) * 64 + l]) +
               a2 * bf2f(jkB[((long)2 * N + nn) * 64 + l]) +
               a3 * bf2f(jkB[((long)3 * N + nn) * 64 + l]);
    feS[w][l] = fe;
    __syncthreads();
    float logit = 0.f;
    if (l < 40)
        for (int c = 0; c < 64; ++c) logit += feS[w][c] * Wout[l * 64 + c];
    float v = (l < 40) ? logit : -1e30f;
    for (int off = 32; off; off >>= 1) v = fmaxf(v, __shfl_xor(v, off));
    float ex = (l < 40) ? __expf(logit - v) : 0.f;
    for (int off = 32; off; off >>= 1) ex += __shfl_xor(ex, off);
    if (ok && l < 40) out[n * 40 + l] = logit - v - __logf(ex);
}

// ---------------------------------------------------------------------------
extern "C" void kernel_launch(void* const* d_in, const int* in_sizes, int n_in,
                              void* d_out, int out_size, void* d_ws, size_t ws_size,
                              hipStream_t stream)
{
    const float* x        = (const float*)d_in[0];
    const int*   eig      = (const int*)d_in[1];
    const float* eag      = (const float*)d_in[2];
    const int*   eilg     = (const int*)d_in[3];
    const float* ealg     = (const float*)d_in[4];
    const float* W_feat   = (const float*)d_in[5];
    const float* W_msg    = (const float*)d_in[6];
    const float* W_lg2g   = (const float*)d_in[7];
    const float* b_lg2g   = (const float*)d_in[8];
    const float* W_msg_l  = (const float*)d_in[9];
    const float* Wih_f    = (const float*)d_in[10];
    const float* Whh_f    = (const float*)d_in[11];
    const float* bih_f    = (const float*)d_in[12];
    const float* bhh_f    = (const float*)d_in[13];
    const float* Wih_b    = (const float*)d_in[14];
    const float* Whh_b    = (const float*)d_in[15];
    const float* bih_b    = (const float*)d_in[16];
    const float* bhh_b    = (const float*)d_in[17];
    const float* W_att    = (const float*)d_in[18];
    const float* W_out    = (const float*)d_in[20];

    int  N   = in_sizes[0] / 128;
    long Eg  = in_sizes[1] / 2;
    long Elg = in_sizes[3] / 2;

    char* wp = (char*)d_ws;
    auto alloc = [&](size_t bytes) -> char* {
        char* p = wp; wp += (bytes + 255) & ~(size_t)255; return p;
    };
    u16*   jkB    = (u16*)  alloc((size_t)4 * N * 64 * 2);
    u16*   mA     = (u16*)  alloc((size_t)Eg * 64 * 2);
    u16*   mB     = (u16*)  alloc((size_t)Eg * 64 * 2);
    float* scores = (float*)alloc((size_t)2 * N * 4 * 4);
    u16*   WhhB   = (u16*)  alloc((size_t)2 * 65536 * 2);
    u16*   WihB   = (u16*)  alloc((size_t)2 * 32768 * 2);
    float* BS     = (float*)alloc((size_t)2 * 512 * 4);
    u16*   WfeatB = (u16*)  alloc((size_t)8192 * 2);
    u16*   WmsgB  = (u16*)  alloc((size_t)9216 * 2);
    u16*   WmsgLB = (u16*)  alloc((size_t)18432 * 2);
    u16*   Wlg2gB = (u16*)  alloc((size_t)4096 * 2);
    u32*   off_g  = (u32*)  alloc((size_t)(N + 1) * 4);
    int*   list_g = (int*)  alloc((size_t)Eg * 4);
    u32*   off_lg = (u32*)  alloc((size_t)(Eg + 1) * 4);
    int*   list_lg= (int*)  alloc((size_t)Elg * 4);
    u32*   part   = (u32*)  alloc((size_t)1024 * 4);

    prep_w<<<928, 256, 0, stream>>>(Whh_f, Whh_b, Wih_f, Wih_b,
                                    bih_f, bhh_f, bih_b, bhh_b,
                                    W_feat, W_msg, W_msg_l, W_lg2g,
                                    WhhB, WihB, BS,
                                    WfeatB, WmsgB, WmsgLB, Wlg2gB);
    // ---- CSR build: both graphs ----
    hipMemsetAsync(off_g, 0, (size_t)(N + 1) * 4, stream);
    hipMemsetAsync(off_lg, 0, (size_t)(Eg + 1) * 4, stream);
    {
        long Emax = (Eg > Elg) ? Eg : Elg;
        count2<<<(int)((Emax + 255) / 256), 256, 0, stream>>>(
            eig + Eg, off_g, Eg, eilg + Elg, off_lg, Elg);
    }
    {
        int nb = (N + 1023) / 1024;
        scan1<<<nb, 256, 0, stream>>>(off_g, part, N);
        scan2<<<1, 1024, 0, stream>>>(part, nb, off_g + N);
        scan3<<<nb, 256, 0, stream>>>(off_g, part, N);
    }
    {
        int nb = (int)((Eg + 1023) / 1024);
        scan1<<<nb, 256, 0, stream>>>(off_lg, part, (int)Eg);
        scan2<<<1, 1024, 0, stream>>>(part, nb, off_lg + Eg);
        scan3<<<nb, 256, 0, stream>>>(off_lg, part, (int)Eg);
    }
    {
        long Emax = (Eg > Elg) ? Eg : Elg;
        fill2<<<(int)((Emax + 255) / 256), 256, 0, stream>>>(
            eig + Eg, off_g, list_g, Eg, eilg + Elg, off_lg, list_lg, Elg);
    }

    // jk0 = relu(x @ W_feat^T)
    rowgemm<128, true, false><<<(N + 63) / 64, 256, 0, stream>>>(
        x, WfeatB, nullptr, nullptr, jkB, N);
    // initial msgs -> mA
    edge_msg_init2<<<(int)((Eg + 127) / 128), 512, 0, stream>>>(
        jkB, eig, eag, WmsgB, mA, Eg);
    // jk1 = gather(mA) @ W_lg2g^T + deg*b   (fused)
    gather_gw<<<(N + 3) / 4, 256, 0, stream>>>(
        mA, list_g, off_g, Wlg2gB, b_lg2g, 1, jkB + (size_t)N * 64, N);
    // ---- linegraph layer 0: mA -> mB ----
    zero_fill<<<(int)((Eg * 8 + 255) / 256), 256, 0, stream>>>(off_lg, mB, Eg);
    edge_msg_lg2<<<(int)((Elg + 127) / 128), 512, 0, stream>>>(
        mA, eilg, ealg, WmsgLB, list_lg, mB, Elg);
    gather_gw<<<(N + 3) / 4, 256, 0, stream>>>(
        mB, list_g, off_g, Wlg2gB, b_lg2g, 0, jkB + (size_t)2 * N * 64, N);
    // ---- linegraph layer 1: mB -> mA ----
    zero_fill<<<(int)((Eg * 8 + 255) / 256), 256, 0, stream>>>(off_lg, mA, Eg);
    edge_msg_lg2<<<(int)((Elg + 127) / 128), 512, 0, stream>>>(
        mB, eilg, ealg, WmsgLB + 9216, list_lg, mA, Elg);
    gather_gw<<<(N + 3) / 4, 256, 0, stream>>>(
        mA, list_g, off_g, Wlg2gB, b_lg2g, 0, jkB + (size_t)3 * N * 64, N);
    // ---- JK bidirectional LSTM ----
    {
        int ntiles = (N + 63) / 64;
        lstm3<<<dim3(ntiles, 2), 512, 0, stream>>>(
            jkB, WhhB, WihB, BS, W_att, scores, N);
    }
    final_kernel<<<(N + 3) / 4, 256, 0, stream>>>(
        jkB, scores, W_out, (float*)d_out, N);
}

// Round 12
// 987.947 us; speedup vs baseline: 1.0547x; 1.0146x over previous
//
#include <hip/hip_runtime.h>

typedef unsigned short u16;
typedef unsigned int u32;
typedef __attribute__((ext_vector_type(8))) short bf16x8;
typedef __attribute__((ext_vector_type(4))) float f32x4;

#define MFMA(a, b, c) __builtin_amdgcn_mfma_f32_16x16x32_bf16(a, b, c, 0, 0, 0)

__device__ __forceinline__ u16 f2bf(float x) {
    union { float f; u32 u; } v; v.f = x;
    u32 r = (v.u + 0x7FFFu + ((v.u >> 16) & 1u)) >> 16;
    return (u16)r;
}
__device__ __forceinline__ float bf2f(u16 b) {
    union { u32 u; float f; } v; v.u = ((u32)b) << 16;
    return v.f;
}
__device__ __forceinline__ void casAddPair(u32* w, float lo, float hi) {
    u32 old = *w, assumed;
    do {
        assumed = old;
        u32 des = (u32)f2bf(bf2f((u16)(assumed & 0xFFFFu)) + lo) |
                  ((u32)f2bf(bf2f((u16)(assumed >> 16)) + hi) << 16);
        if (des == assumed) break;
        old = atomicCAS(w, assumed, des);
    } while (old != assumed);
}

// ---------------------------------------------------------------------------
// prep: convert LSTM weights to bf16 (gate rows pre-scaled by log2e, g-gate by
// 2*log2e for native v_exp_f32), combine biases, and pre-convert the other
// weight matrices to bf16 so per-block staging is pure vector copies.
__global__ __launch_bounds__(256) void prep_w(
    const float* __restrict__ Whh_f, const float* __restrict__ Whh_b,
    const float* __restrict__ Wih_f, const float* __restrict__ Wih_b,
    const float* __restrict__ bih_f, const float* __restrict__ bhh_f,
    const float* __restrict__ bih_b, const float* __restrict__ bhh_b,
    const float* __restrict__ W_feat, const float* __restrict__ W_msg,
    const float* __restrict__ W_msg_l, const float* __restrict__ W_lg2g,
    u16* __restrict__ WhhB, u16* __restrict__ WihB, float* __restrict__ BS,
    u16* __restrict__ WfeatB, u16* __restrict__ WmsgB,
    u16* __restrict__ WmsgLB, u16* __restrict__ Wlg2gB)
{
    const float L2E = 1.4426950408889634f;
    int i = blockIdx.x * 256 + threadIdx.x;
    if (i < 131072) {
        int d = i >> 16, r = i & 65535;
        float s = (((r >> 14) & 3) == 2) ? 2.f * L2E : L2E;
        WhhB[i] = f2bf(s * (d ? Whh_b[r] : Whh_f[r]));
    } else if (i < 196608) {
        int i2 = i - 131072; int d = i2 >> 15, r = i2 & 32767;
        float s = (((r >> 13) & 3) == 2) ? 2.f * L2E : L2E;
        WihB[i2] = f2bf(s * (d ? Wih_b[r] : Wih_f[r]));
    } else if (i < 197632) {
        int i3 = i - 196608; int d = i3 >> 9, g = i3 & 511;
        float s = (((g >> 7) & 3) == 2) ? 2.f * L2E : L2E;
        BS[i3] = s * (d ? (bih_b[g] + bhh_b[g]) : (bih_f[g] + bhh_f[g]));
    } else if (i < 205824) {
        int j = i - 197632; WfeatB[j] = f2bf(W_feat[j]);
    } else if (i < 215040) {
        int j = i - 205824; WmsgB[j] = f2bf(W_msg[j]);
    } else if (i < 233472) {
        int j = i - 215040; WmsgLB[j] = f2bf(W_msg_l[j]);
    } else if (i < 237568) {
        int j = i - 233472; Wlg2gB[j] = f2bf(W_lg2g[j]);
    }
}

// ---------------------------------------------------------------------------
// CSR build
__global__ __launch_bounds__(256) void count_kernel(const int* __restrict__ dst,
                                                    u32* __restrict__ cnt, long E)
{
    long i = (long)blockIdx.x * 256 + threadIdx.x;
    if (i < E) atomicAdd(&cnt[dst[i]], 1u);
}

__global__ __launch_bounds__(256) void scan1(const u32* __restrict__ a,
                                             u32* __restrict__ part, int n)
{
    __shared__ u32 ts[256];
    int b = blockIdx.x, t = threadIdx.x;
    long i0 = (long)b * 1024 + t * 4;
    u32 s = 0;
#pragma unroll
    for (int k = 0; k < 4; ++k) { long i = i0 + k; if (i < n) s += a[i]; }
    ts[t] = s; __syncthreads();
    for (int off = 1; off < 256; off <<= 1) {
        u32 x = (t >= off) ? ts[t - off] : 0u;
        __syncthreads(); ts[t] += x; __syncthreads();
    }
    if (t == 255) part[b] = ts[255];
}

__global__ __launch_bounds__(1024) void scan2(u32* __restrict__ part, int nb,
                                              u32* __restrict__ total_out)
{
    __shared__ u32 ts[1024];
    int t = threadIdx.x;
    u32 v = (t < nb) ? part[t] : 0u;
    ts[t] = v; __syncthreads();
    for (int off = 1; off < 1024; off <<= 1) {
        u32 x = (t >= off) ? ts[t - off] : 0u;
        __syncthreads(); ts[t] += x; __syncthreads();
    }
    if (t < nb) part[t] = ts[t] - v;
    if (t == 1023 && total_out) *total_out = ts[1023];
}

__global__ __launch_bounds__(256) void scan3(u32* __restrict__ a,
                                             const u32* __restrict__ part, int n)
{
    __shared__ u32 ts[256];
    int b = blockIdx.x, t = threadIdx.x;
    long i0 = (long)b * 1024 + t * 4;
    u32 v[4]; u32 s = 0;
#pragma unroll
    for (int k = 0; k < 4; ++k) { long i = i0 + k; v[k] = (i < n) ? a[i] : 0u; s += v[k]; }
    ts[t] = s; __syncthreads();
    for (int off = 1; off < 256; off <<= 1) {
        u32 x = (t >= off) ? ts[t - off] : 0u;
        __syncthreads(); ts[t] += x; __syncthreads();
    }
    u32 run = part[b] + ts[t] - s;
#pragma unroll
    for (int k = 0; k < 4; ++k) {
        long i = i0 + k;
        if (i < n) { u32 x = v[k]; a[i] = run; run += x; }
    }
}

__global__ __launch_bounds__(256) void fill_kernel(const int* __restrict__ dst,
                                                   u32* __restrict__ off,
                                                   int* __restrict__ list, long E)
{
    long i = (long)blockIdx.x * 256 + threadIdx.x;
    if (i < E) {
        u32 pos = atomicAdd(&off[dst[i]], 1u);
        list[pos] = (int)i;
    }
}

// ---------------------------------------------------------------------------
__global__ __launch_bounds__(256) void zero_fill(const u32* __restrict__ offc,
                                                 u16* __restrict__ outb, long NB)
{
    long idx = (long)blockIdx.x * 256 + threadIdx.x;
    long n = idx >> 3; int q = (int)(idx & 7);
    if (n >= NB) return;
    u32 s = n ? offc[n - 1] : 0u;
    u32 e = offc[n];
    bool need = (s == e) || ((s >> 7) != ((e - 1) >> 7));
    if (need) *(uint4*)(outb + n * 64 + q * 8) = make_uint4(0, 0, 0, 0);
}

// ---------------------------------------------------------------------------
// rowgemm: outb[M x 64] (bf16) = act(in[M x K] @ W[64 x K]^T (+ bias*scale))
template <int K, bool RELU, bool INBF16>
__global__ __launch_bounds__(256) void rowgemm(
    const void* __restrict__ in, const u16* __restrict__ W,
    const float* __restrict__ bias, const float* __restrict__ bias_scale,
    u16* __restrict__ outb, int M)
{
    constexpr int KP = K + 8;
    constexpr int K8 = K / 8;
    __shared__ u16 inS[64 * KP];
    __shared__ u16 WS[64 * KP];
    int t = threadIdx.x;
    long rb = (long)blockIdx.x * 64;
    for (int i = t; i < 64 * K8; i += 256) {
        int c = i / K8, q = i - c * K8;
        *(uint4*)&WS[c * KP + q * 8] = *(const uint4*)&W[c * K + q * 8];
    }
    if (INBF16) {
        const u16* inb = (const u16*)in;
        for (int i = t; i < 64 * K8; i += 256) {
            int r = i / K8, q = i - r * K8;
            long gr = rb + r;
            uint4 v = make_uint4(0, 0, 0, 0);
            if (gr < M) v = *(const uint4*)&inb[gr * (long)K + q * 8];
            *(uint4*)&inS[r * KP + q * 8] = v;
        }
    } else {
        const float* inf = (const float*)in;
        for (int i = t; i < 64 * K; i += 256) {
            int r = i / K, k = i - r * K;
            long gr = rb + r;
            inS[r * KP + k] = (gr < M) ? f2bf(inf[gr * (long)K + k]) : (u16)0;
        }
    }
    __syncthreads();
    int l = t & 63, w = t >> 6, lr = l & 15, lq = l >> 4;
    f32x4 acc[4];
#pragma unroll
    for (int i = 0; i < 4; ++i) acc[i] = (f32x4){0.f, 0.f, 0.f, 0.f};
#pragma unroll
    for (int kc = 0; kc < K; kc += 32) {
        bf16x8 a = *(const bf16x8*)&inS[(w * 16 + lr) * KP + kc + lq * 8];
#pragma unroll
        for (int ct = 0; ct < 4; ++ct) {
            bf16x8 b = *(const bf16x8*)&WS[(ct * 16 + lr) * KP + kc + lq * 8];
            acc[ct] = MFMA(a, b, acc[ct]);
        }
    }
#pragma unroll
    for (int ct = 0; ct < 4; ++ct)
#pragma unroll
        for (int r = 0; r < 4; ++r) {
            long gr = rb + w * 16 + lq * 4 + r;
            if (gr < M) {
                int c = ct * 16 + lr;
                float v = acc[ct][r];
                if (bias) v += bias[c] * (bias_scale ? bias_scale[gr] : 1.f);
                if (RELU) v = fmaxf(v, 0.f);
                outb[gr * 64 + c] = f2bf(v);
            }
        }
}

// ---------------------------------------------------------------------------
// edge_msg_init2: direct-gather A-fragments; W pre-converted bf16, attr f32.
__global__ __launch_bounds__(512, 4) void edge_msg_init2(
    const u16* __restrict__ feat, const int* __restrict__ ei,
    const float* __restrict__ attr, const u16* __restrict__ W,
    u16* __restrict__ outb, long E)
{
    __shared__ u16 WS[64 * 168];
    __shared__ u16 eds[128 * 64];
    int t = threadIdx.x;
    long eb = (long)blockIdx.x * 128;
    for (int i = t; i < 1152; i += 512) {                 // 64*144/8
        int c = i / 18, q = i - c * 18;
        *(uint4*)&WS[c * 168 + q * 8] = *(const uint4*)&W[c * 144 + q * 8];
    }
    if (t < 192) {                                        // 64*24/8 zero pad
        int c = t / 3, q = t - c * 3;
        *(uint4*)&WS[c * 168 + 144 + q * 8] = make_uint4(0, 0, 0, 0);
    }
    int w = t >> 6, l = t & 63, lr = l & 15, lq = l >> 4;
    long e = eb + w * 16 + lr;
    long ec = (e < E) ? e : (E - 1);
    int src = ei[ec], dst = ei[E + ec];
    bf16x8 A[5];
    {
        const uint4* sp = (const uint4*)(feat + (long)src * 64);
        const uint4* dp = (const uint4*)(feat + (long)dst * 64);
        *(uint4*)&A[0] = sp[lq];
        *(uint4*)&A[1] = sp[4 + lq];
        *(uint4*)&A[2] = dp[lq];
        *(uint4*)&A[3] = dp[4 + lq];
        uint4 pv = make_uint4(0, 0, 0, 0);
        if (lq < 2) {
            const float4* ap = (const float4*)(attr + ec * 16) + lq * 2;
            float4 b0 = ap[0], b1 = ap[1];
            pv.x = (u32)f2bf(b0.x) | ((u32)f2bf(b0.y) << 16);
            pv.y = (u32)f2bf(b0.z) | ((u32)f2bf(b0.w) << 16);
            pv.z = (u32)f2bf(b1.x) | ((u32)f2bf(b1.y) << 16);
            pv.w = (u32)f2bf(b1.z) | ((u32)f2bf(b1.w) << 16);
        }
        *(uint4*)&A[4] = pv;
    }
    __syncthreads();
    f32x4 acc[4];
#pragma unroll
    for (int ct = 0; ct < 4; ++ct) acc[ct] = (f32x4){0.f, 0.f, 0.f, 0.f};
#pragma unroll
    for (int kc = 0; kc < 5; ++kc) {
#pragma unroll
        for (int ct = 0; ct < 4; ++ct) {
            bf16x8 b = *(const bf16x8*)&WS[(ct * 16 + lr) * 168 + kc * 32 + lq * 8];
            acc[ct] = MFMA(A[kc], b, acc[ct]);
        }
    }
#pragma unroll
    for (int ct = 0; ct < 4; ++ct)
#pragma unroll
        for (int r = 0; r < 4; ++r) {
            int row = w * 16 + lq * 4 + r;
            int col = ct * 16 + lr;
            eds[row * 64 + col] = f2bf(fmaxf(acc[ct][r], 0.f));
        }
    __syncthreads();
    for (int j = t; j < 1024; j += 512) {
        int le = j >> 3, q = j & 7;
        long e2 = eb + le;
        if (e2 < E)
            *(uint4*)(outb + e2 * 64 + q * 8) = *(const uint4*)&eds[le * 64 + q * 8];
    }
}

// ---------------------------------------------------------------------------
// edge_msg_lg2: dst-sorted (CSR) order, segmented reduction epilogue.
__global__ __launch_bounds__(512, 4) void edge_msg_lg2(
    const u16* __restrict__ feat, const int* __restrict__ ei,
    const float* __restrict__ attr, const u16* __restrict__ W,
    const int* __restrict__ list, u16* __restrict__ outb, long E)
{
    __shared__ u16 WS[64 * 168];
    __shared__ u16 eds[128 * 64];
    __shared__ int dstS[128];
    __shared__ int idS[128];
    __shared__ int srcS[128];
    __shared__ int dprevS, dnextS;
    int t = threadIdx.x;
    long pb = (long)blockIdx.x * 128;
    for (int i = t; i < 1152; i += 512) {
        int c = i / 18, q = i - c * 18;
        *(uint4*)&WS[c * 168 + q * 8] = *(const uint4*)&W[c * 144 + q * 8];
    }
    if (t < 192) {
        int c = t / 3, q = t - c * 3;
        *(uint4*)&WS[c * 168 + 144 + q * 8] = make_uint4(0, 0, 0, 0);
    }
    if (t < 128) {
        long p = pb + t;
        int id = (p < E) ? list[p] : -1;
        idS[t] = id;
        srcS[t] = (id >= 0) ? ei[id] : 0;
        dstS[t] = (id >= 0) ? ei[E + id] : -1;
    } else if (t == 128) {
        dprevS = (pb > 0) ? ei[E + list[pb - 1]] : -2;
    } else if (t == 129) {
        dnextS = (pb + 128 < E) ? ei[E + list[pb + 128]] : -2;
    }
    __syncthreads();
    int w = t >> 6, l = t & 63, lr = l & 15, lq = l >> 4;
    int el = w * 16 + lr;
    int id = idS[el];
    long idc = (id >= 0) ? (long)id : 0;
    int src = srcS[el];
    int dst = (dstS[el] >= 0) ? dstS[el] : 0;
    bf16x8 A[5];
    {
        const uint4* sp = (const uint4*)(feat + (long)src * 64);
        const uint4* dp = (const uint4*)(feat + (long)dst * 64);
        *(uint4*)&A[0] = sp[lq];
        *(uint4*)&A[1] = sp[4 + lq];
        *(uint4*)&A[2] = dp[lq];
        *(uint4*)&A[3] = dp[4 + lq];
        uint4 pv = make_uint4(0, 0, 0, 0);
        if (lq < 2) {
            const float4* ap = (const float4*)(attr + idc * 16) + lq * 2;
            float4 b0 = ap[0], b1 = ap[1];
            pv.x = (u32)f2bf(b0.x) | ((u32)f2bf(b0.y) << 16);
            pv.y = (u32)f2bf(b0.z) | ((u32)f2bf(b0.w) << 16);
            pv.z = (u32)f2bf(b1.x) | ((u32)f2bf(b1.y) << 16);
            pv.w = (u32)f2bf(b1.z) | ((u32)f2bf(b1.w) << 16);
        }
        *(uint4*)&A[4] = pv;
    }
    f32x4 acc[4];
#pragma unroll
    for (int ct = 0; ct < 4; ++ct) acc[ct] = (f32x4){0.f, 0.f, 0.f, 0.f};
#pragma unroll
    for (int kc = 0; kc < 5; ++kc) {
#pragma unroll
        for (int ct = 0; ct < 4; ++ct) {
            bf16x8 b = *(const bf16x8*)&WS[(ct * 16 + lr) * 168 + kc * 32 + lq * 8];
            acc[ct] = MFMA(A[kc], b, acc[ct]);
        }
    }
#pragma unroll
    for (int ct = 0; ct < 4; ++ct)
#pragma unroll
        for (int r = 0; r < 4; ++r) {
            int row = w * 16 + lq * 4 + r;
            int col = ct * 16 + lr;
            eds[row * 64 + col] = f2bf(fmaxf(acc[ct][r], 0.f));
        }
    __syncthreads();
    for (int j = t; j < 4096; j += 512) {
        int le = j >> 5, wd = j & 31;
        int d = dstS[le];
        if (d < 0) continue;
        if (le > 0 && dstS[le - 1] == d) continue;
        float lo = 0.f, hi = 0.f;
        int le2 = le;
        do {
            u32 pair = *(const u32*)&eds[le2 * 64 + wd * 2];
            lo += bf2f((u16)(pair & 0xFFFFu));
            hi += bf2f((u16)(pair >> 16));
            ++le2;
        } while (le2 < 128 && dstS[le2] == d);
        bool bprev = (le == 0 && dprevS == d);
        bool bnext = (le2 == 128 && dnextS == d);
        u32* dw = (u32*)(outb + (long)d * 64 + wd * 2);
        if (bprev || bnext) {
            casAddPair(dw, lo, hi);
        } else {
            *dw = (u32)f2bf(lo) | ((u32)f2bf(hi) << 16);
        }
    }
}

// ---------------------------------------------------------------------------
// gather_gw: FUSED gather + 64x64 linear. One wave per node (halves do
// even/odd list positions); the serial L3-random edge loop is the latency
// bottleneck -> 4-deep manual unroll issues 4 independent pair-loads per
// iteration (4x latency hiding). f32 agg -> LDS -> 64-lane matvec against
// transposed W (pad 66). out = agg@W^T + b*scale.
__global__ __launch_bounds__(256) void gather_gw(
    const u16* __restrict__ m, const int* __restrict__ list,
    const u32* __restrict__ offc, const u16* __restrict__ Wg,
    const float* __restrict__ bias, int useDeg,
    u16* __restrict__ outb, int N)
{
    __shared__ u16 WS[64 * 66];       // transposed: WS[k*66+r] = W[r][k]
    __shared__ float aggS[4][64];
    __shared__ float degS[4];
    int t = threadIdx.x;
    for (int i = t; i < 4096; i += 256) {
        int r = i >> 6, k = i & 63;
        WS[k * 66 + r] = Wg[i];
    }
    int wv = t >> 6, l = t & 63, c = l & 31, half = l >> 5;
    long n = (long)blockIdx.x * 4 + wv;
    long nn = (n < N) ? n : (long)(N - 1);
    u32 start = nn ? offc[nn - 1] : 0u;
    u32 end = offc[nn];
    float s0 = 0.f, s1 = 0.f, s2 = 0.f, s3 = 0.f;
    float t0 = 0.f, t1 = 0.f, t2 = 0.f, t3 = 0.f;
    u32 i = start + half;
    for (; i + 6 < end; i += 8) {     // 4 stride-2 elems per half-wave
        int e0 = list[i], e1 = list[i + 2], e2 = list[i + 4], e3 = list[i + 6];
        u32 p0 = *(const u32*)&m[(long)e0 * 64 + c * 2];
        u32 p1 = *(const u32*)&m[(long)e1 * 64 + c * 2];
        u32 p2 = *(const u32*)&m[(long)e2 * 64 + c * 2];
        u32 p3 = *(const u32*)&m[(long)e3 * 64 + c * 2];
        s0 += bf2f((u16)(p0 & 0xFFFFu)); t0 += bf2f((u16)(p0 >> 16));
        s1 += bf2f((u16)(p1 & 0xFFFFu)); t1 += bf2f((u16)(p1 >> 16));
        s2 += bf2f((u16)(p2 & 0xFFFFu)); t2 += bf2f((u16)(p2 >> 16));
        s3 += bf2f((u16)(p3 & 0xFFFFu)); t3 += bf2f((u16)(p3 >> 16));
    }
    for (; i < end; i += 2) {
        int e = list[i];
        u32 pair = *(const u32*)&m[(long)e * 64 + c * 2];
        s0 += bf2f((u16)(pair & 0xFFFFu));
        t0 += bf2f((u16)(pair >> 16));
    }
    float slo = (s0 + s1) + (s2 + s3);
    float shi = (t0 + t1) + (t2 + t3);
    slo += __shfl_xor(slo, 32);
    shi += __shfl_xor(shi, 32);
    if (half == 0) { aggS[wv][c * 2] = slo; aggS[wv][c * 2 + 1] = shi; }
    if (l == 0) degS[wv] = (float)(end - start);
    __syncthreads();
    float acc = 0.f;
#pragma unroll 8
    for (int k = 0; k < 64; ++k)
        acc += aggS[wv][k] * bf2f(WS[k * 66 + l]);
    float scale = useDeg ? degS[wv] : 1.f;
    acc += bias[l] * scale;
    if (n < N) outb[n * 64 + l] = f2bf(acc);
}

// ---------------------------------------------------------------------------
// lstm3: bidirectional JK-LSTM, 64 nodes/tile — round-2's proven all-LDS
// dataflow (159 us, VGPR 108, no spill). Structurally done: Wh (64 regs) +
// acc AGPRs put total regs ~172 -> hard 2 waves/SIMD; Whh (128 KB/dir)
// cannot be LDS-resident, so 4 waves/SIMD without spill is infeasible.
__global__ __launch_bounds__(512, 2) void lstm3(
    const u16* __restrict__ jkB, const u16* __restrict__ WhhB,
    const u16* __restrict__ WihB, const float* __restrict__ BS,
    const float* __restrict__ Watt, float* __restrict__ scores,
    int N)
{
    __shared__ u16 hS[64 * 136];         // 17408 B
    __shared__ u16 xS[4][64 * 72];       // 36864 B
    __shared__ u16 WiS[512 * 72];        // 73728 B (padded stride 72)
    __shared__ float bsS[512];           //  2048 B
    __shared__ float part[4 * 64 * 8];   //  8192 B   total 138240 B
    int t = threadIdx.x;
    int dir = blockIdx.y;
    int w = t >> 6, l = t & 63, lr = l & 15, lq = l >> 4;
    const u16* WhhD = WhhB + (long)dir * 65536;
    const u16* WihD = WihB + (long)dir * 32768;
    long n0 = (long)blockIdx.x * 64;

    // stage x for all 4 JK steps
    {
        int n = t >> 3, j = t & 7;
        long gn = n0 + n;
#pragma unroll
        for (int k = 0; k < 4; ++k) {
            uint4 v = make_uint4(0, 0, 0, 0);
            if (gn < N) v = *(const uint4*)&jkB[((long)k * N + gn) * 64 + j * 8];
            *(uint4*)&xS[k][n * 72 + j * 8] = v;
        }
    }
    // stage Wi (512 gate-rows x 64, padded to 72) and bias
#pragma unroll
    for (int i = t; i < 4096; i += 512) {
        int g = i >> 3, q = i & 7;
        *(uint4*)&WiS[g * 72 + q * 8] = *(const uint4*)&WihD[g * 64 + q * 8];
    }
    bsS[t] = BS[dir * 512 + t];

    int grow0 = w * 16 + lq * 4;         // this thread's first hidden unit
    bf16x8 Wh[4][4];
#pragma unroll
    for (int ty = 0; ty < 4; ++ty) {
        int g = ty * 128 + w * 16 + lr;
#pragma unroll
        for (int kc = 0; kc < 4; ++kc)
            Wh[ty][kc] = *(const bf16x8*)&WhhD[g * 128 + kc * 32 + lq * 8];
    }
    float4 Wa4 = *(const float4*)&Watt[dir * 128 + grow0];
    float* scOut = scores + (long)dir * N * 4;

    float creg[4][4] = {};
    __syncthreads();                     // xS / WiS / bsS visible

#pragma unroll 1
    for (int s = 0; s < 4; ++s) {
        int tt = dir ? (3 - s) : s;
        float u[4][4];
        // ---------------- pass A: gates i (0) and g (2) -> u ----------------
        {
            f32x4 acc[2][4];
            f32x4 bi = *(const f32x4*)&bsS[grow0];
            f32x4 bg = *(const f32x4*)&bsS[256 + grow0];
#pragma unroll
            for (int nt = 0; nt < 4; ++nt) { acc[0][nt] = bi; acc[1][nt] = bg; }
            if (s) {
#pragma unroll
                for (int kc = 0; kc < 4; ++kc) {
                    bf16x8 a[4];
#pragma unroll
                    for (int nt = 0; nt < 4; ++nt)
                        a[nt] = *(const bf16x8*)&hS[(nt * 16 + lr) * 136 + kc * 32 + lq * 8];
#pragma unroll
                    for (int nt = 0; nt < 4; ++nt) {
                        acc[0][nt] = MFMA(Wh[0][kc], a[nt], acc[0][nt]);
                        acc[1][nt] = MFMA(Wh[2][kc], a[nt], acc[1][nt]);
                    }
                }
            }
#pragma unroll
            for (int kc = 0; kc < 2; ++kc) {
                bf16x8 wi = *(const bf16x8*)&WiS[(w * 16 + lr) * 72 + kc * 32 + lq * 8];
                bf16x8 wg = *(const bf16x8*)&WiS[(256 + w * 16 + lr) * 72 + kc * 32 + lq * 8];
                bf16x8 a[4];
#pragma unroll
                for (int nt = 0; nt < 4; ++nt)
                    a[nt] = *(const bf16x8*)&xS[tt][(nt * 16 + lr) * 72 + kc * 32 + lq * 8];
#pragma unroll
                for (int nt = 0; nt < 4; ++nt) {
                    acc[0][nt] = MFMA(wi, a[nt], acc[0][nt]);
                    acc[1][nt] = MFMA(wg, a[nt], acc[1][nt]);
                }
            }
#pragma unroll
            for (int nt = 0; nt < 4; ++nt)
#pragma unroll
                for (int r = 0; r < 4; ++r) {
                    float si = __builtin_amdgcn_rcpf(
                        1.f + __builtin_amdgcn_exp2f(-acc[0][nt][r]));
                    float tg = 2.f * __builtin_amdgcn_rcpf(
                        1.f + __builtin_amdgcn_exp2f(-acc[1][nt][r])) - 1.f;
                    u[nt][r] = si * tg;
                }
        }
        // ---------------- pass B: gates f (1) and o (3) -> c, h -------------
        {
            f32x4 acc[2][4];
            f32x4 bf = *(const f32x4*)&bsS[128 + grow0];
            f32x4 bo = *(const f32x4*)&bsS[384 + grow0];
#pragma unroll
            for (int nt = 0; nt < 4; ++nt) { acc[0][nt] = bf; acc[1][nt] = bo; }
            if (s) {
#pragma unroll
                for (int kc = 0; kc < 4; ++kc) {
                    bf16x8 a[4];
#pragma unroll
                    for (int nt = 0; nt < 4; ++nt)
                        a[nt] = *(const bf16x8*)&hS[(nt * 16 + lr) * 136 + kc * 32 + lq * 8];
#pragma unroll
                    for (int nt = 0; nt < 4; ++nt) {
                        acc[0][nt] = MFMA(Wh[1][kc], a[nt], acc[0][nt]);
                        acc[1][nt] = MFMA(Wh[3][kc], a[nt], acc[1][nt]);
                    }
                }
            }
#pragma unroll
            for (int kc = 0; kc < 2; ++kc) {
                bf16x8 wf = *(const bf16x8*)&WiS[(128 + w * 16 + lr) * 72 + kc * 32 + lq * 8];
                bf16x8 wo = *(const bf16x8*)&WiS[(384 + w * 16 + lr) * 72 + kc * 32 + lq * 8];
                bf16x8 a[4];
#pragma unroll
                for (int nt = 0; nt < 4; ++nt)
                    a[nt] = *(const bf16x8*)&xS[tt][(nt * 16 + lr) * 72 + kc * 32 + lq * 8];
#pragma unroll
                for (int nt = 0; nt < 4; ++nt) {
                    acc[0][nt] = MFMA(wf, a[nt], acc[0][nt]);
                    acc[1][nt] = MFMA(wo, a[nt], acc[1][nt]);
                }
            }
            if (s) __syncthreads();      // all hS reads (A+B) done before overwrite
#pragma unroll
            for (int nt = 0; nt < 4; ++nt) {
                float hv[4];
#pragma unroll
                for (int r = 0; r < 4; ++r) {
                    float sf = __builtin_amdgcn_rcpf(
                        1.f + __builtin_amdgcn_exp2f(-acc[0][nt][r]));
                    float c = sf * creg[nt][r] + u[nt][r];
                    float so = __builtin_amdgcn_rcpf(
                        1.f + __builtin_amdgcn_exp2f(-acc[1][nt][r]));
                    float th = 2.f * __builtin_amdgcn_rcpf(
                        1.f + __builtin_amdgcn_exp2f(-2.8853900817779268f * c)) - 1.f;
                    creg[nt][r] = c;
                    hv[r] = so * th;
                }
                // attention partial over this thread's 4 hidden units (f32 h)
                float p = hv[0] * Wa4.x + hv[1] * Wa4.y + hv[2] * Wa4.z + hv[3] * Wa4.w;
                p += __shfl_xor(p, 16);
                p += __shfl_xor(p, 32);  // sum over lq -> wave's 16 units
                if (lq == 0) part[(tt * 64 + nt * 16 + lr) * 8 + w] = p;
                if (s < 3) {             // h3 feeds nothing but attention
                    u32 p0, p1;
                    asm("v_cvt_pk_bf16_f32 %0, %1, %2" : "=v"(p0) : "v"(hv[0]), "v"(hv[1]));
                    asm("v_cvt_pk_bf16_f32 %0, %1, %2" : "=v"(p1) : "v"(hv[2]), "v"(hv[3]));
                    *(uint2*)&hS[(nt * 16 + lr) * 136 + grow0] = make_uint2(p0, p1);
                }
            }
        }
        if (s < 3) __syncthreads();      // new h visible
    }
    __syncthreads();                     // part visible
    if (t < 256) {
        int tt = t >> 6, node = t & 63;
        long gn = n0 + node;
        if (gn < N) {
            const float4* pp = (const float4*)&part[(tt * 64 + node) * 8];
            float4 a = pp[0], b = pp[1];
            scOut[gn * 4 + tt] = a.x + a.y + a.z + a.w + b.x + b.y + b.z + b.w;
        }
    }
}

// ---------------------------------------------------------------------------
__global__ __launch_bounds__(256) void final_kernel(
    const u16* __restrict__ jkB, const float* __restrict__ scores,
    const float* __restrict__ Wout, float* __restrict__ out, int N)
{
    __shared__ float feS[4][64];
    int t = threadIdx.x, l = t & 63, w = t >> 6;
    long n = (long)blockIdx.x * 4 + w;
    bool ok = (n < N);
    long nn = ok ? n : (long)(N - 1);
    float sc[4];
#pragma unroll
    for (int tt = 0; tt < 4; ++tt)
        sc[tt] = scores[nn * 4 + tt] + scores[(long)N * 4 + nn * 4 + tt];
    float m = fmaxf(fmaxf(sc[0], sc[1]), fmaxf(sc[2], sc[3]));
    float e0 = __expf(sc[0] - m), e1 = __expf(sc[1] - m);
    float e2 = __expf(sc[2] - m), e3 = __expf(sc[3] - m);
    float den = e0 + e1 + e2 + e3;
    float a0 = e0 / den, a1 = e1 / den, a2 = e2 / den, a3 = e3 / den;
    float fe = a0 * bf2f(jkB[nn * 64 + l]) + a1 * bf2f(jkB[((long)N + nn) * 64 + l]) +
               a2 * bf2f(jkB[((long)2 * N + nn) * 64 + l]) +
               a3 * bf2f(jkB[((long)3 * N + nn) * 64 + l]);
    feS[w][l] = fe;
    __syncthreads();
    float logit = 0.f;
    if (l < 40)
        for (int c = 0; c < 64; ++c) logit += feS[w][c] * Wout[l * 64 + c];
    float v = (l < 40) ? logit : -1e30f;
    for (int off = 32; off; off >>= 1) v = fmaxf(v, __shfl_xor(v, off));
    float ex = (l < 40) ? __expf(logit - v) : 0.f;
    for (int off = 32; off; off >>= 1) ex += __shfl_xor(ex, off);
    if (ok && l < 40) out[n * 40 + l] = logit - v - __logf(ex);
}

// ---------------------------------------------------------------------------
extern "C" void kernel_launch(void* const* d_in, const int* in_sizes, int n_in,
                              void* d_out, int out_size, void* d_ws, size_t ws_size,
                              hipStream_t stream)
{
    const float* x        = (const float*)d_in[0];
    const int*   eig      = (const int*)d_in[1];
    const float* eag      = (const float*)d_in[2];
    const int*   eilg     = (const int*)d_in[3];
    const float* ealg     = (const float*)d_in[4];
    const float* W_feat   = (const float*)d_in[5];
    const float* W_msg    = (const float*)d_in[6];
    const float* W_lg2g   = (const float*)d_in[7];
    const float* b_lg2g   = (const float*)d_in[8];
    const float* W_msg_l  = (const float*)d_in[9];
    const float* Wih_f    = (const float*)d_in[10];
    const float* Whh_f    = (const float*)d_in[11];
    const float* bih_f    = (const float*)d_in[12];
    const float* bhh_f    = (const float*)d_in[13];
    const float* Wih_b    = (const float*)d_in[14];
    const float* Whh_b    = (const float*)d_in[15];
    const float* bih_b    = (const float*)d_in[16];
    const float* bhh_b    = (const float*)d_in[17];
    const float* W_att    = (const float*)d_in[18];
    const float* W_out    = (const float*)d_in[20];

    int  N   = in_sizes[0] / 128;
    long Eg  = in_sizes[1] / 2;
    long Elg = in_sizes[3] / 2;

    char* wp = (char*)d_ws;
    auto alloc = [&](size_t bytes) -> char* {
        char* p = wp; wp += (bytes + 255) & ~(size_t)255; return p;
    };
    u16*   jkB    = (u16*)  alloc((size_t)4 * N * 64 * 2);
    u16*   mA     = (u16*)  alloc((size_t)Eg * 64 * 2);
    u16*   mB     = (u16*)  alloc((size_t)Eg * 64 * 2);
    float* scores = (float*)alloc((size_t)2 * N * 4 * 4);
    u16*   WhhB   = (u16*)  alloc((size_t)2 * 65536 * 2);
    u16*   WihB   = (u16*)  alloc((size_t)2 * 32768 * 2);
    float* BS     = (float*)alloc((size_t)2 * 512 * 4);
    u16*   WfeatB = (u16*)  alloc((size_t)8192 * 2);
    u16*   WmsgB  = (u16*)  alloc((size_t)9216 * 2);
    u16*   WmsgLB = (u16*)  alloc((size_t)18432 * 2);
    u16*   Wlg2gB = (u16*)  alloc((size_t)4096 * 2);
    u32*   off_g  = (u32*)  alloc((size_t)(N + 1) * 4);
    int*   list_g = (int*)  alloc((size_t)Eg * 4);
    u32*   off_lg = (u32*)  alloc((size_t)(Eg + 1) * 4);
    int*   list_lg= (int*)  alloc((size_t)Elg * 4);
    u32*   part   = (u32*)  alloc((size_t)1024 * 4);

    prep_w<<<928, 256, 0, stream>>>(Whh_f, Whh_b, Wih_f, Wih_b,
                                    bih_f, bhh_f, bih_b, bhh_b,
                                    W_feat, W_msg, W_msg_l, W_lg2g,
                                    WhhB, WihB, BS,
                                    WfeatB, WmsgB, WmsgLB, Wlg2gB);
    // ---- CSR build: g-graph (dst over nodes) ----
    hipMemsetAsync(off_g, 0, (size_t)(N + 1) * 4, stream);
    count_kernel<<<(int)((Eg + 255) / 256), 256, 0, stream>>>(eig + Eg, off_g, Eg);
    {
        int nb = (N + 1023) / 1024;
        scan1<<<nb, 256, 0, stream>>>(off_g, part, N);
        scan2<<<1, 1024, 0, stream>>>(part, nb, off_g + N);
        scan3<<<nb, 256, 0, stream>>>(off_g, part, N);
    }
    fill_kernel<<<(int)((Eg + 255) / 256), 256, 0, stream>>>(eig + Eg, off_g, list_g, Eg);
    // ---- CSR build: lg-graph (dst over g-edges) ----
    hipMemsetAsync(off_lg, 0, (size_t)(Eg + 1) * 4, stream);
    count_kernel<<<(int)((Elg + 255) / 256), 256, 0, stream>>>(eilg + Elg, off_lg, Elg);
    {
        int nb = (int)((Eg + 1023) / 1024);
        scan1<<<nb, 256, 0, stream>>>(off_lg, part, (int)Eg);
        scan2<<<1, 1024, 0, stream>>>(part, nb, off_lg + Eg);
        scan3<<<nb, 256, 0, stream>>>(off_lg, part, (int)Eg);
    }
    fill_kernel<<<(int)((Elg + 255) / 256), 256, 0, stream>>>(eilg + Elg, off_lg, list_lg, Elg);

    // jk0 = relu(x @ W_feat^T)
    rowgemm<128, true, false><<<(N + 63) / 64, 256, 0, stream>>>(
        x, WfeatB, nullptr, nullptr, jkB, N);
    // initial msgs -> mA
    edge_msg_init2<<<(int)((Eg + 127) / 128), 512, 0, stream>>>(
        jkB, eig, eag, WmsgB, mA, Eg);
    // jk1 = gather(mA) @ W_lg2g^T + deg*b   (fused)
    gather_gw<<<(N + 3) / 4, 256, 0, stream>>>(
        mA, list_g, off_g, Wlg2gB, b_lg2g, 1, jkB + (size_t)N * 64, N);
    // ---- linegraph layer 0: mA -> mB ----
    zero_fill<<<(int)((Eg * 8 + 255) / 256), 256, 0, stream>>>(off_lg, mB, Eg);
    edge_msg_lg2<<<(int)((Elg + 127) / 128), 512, 0, stream>>>(
        mA, eilg, ealg, WmsgLB, list_lg, mB, Elg);
    gather_gw<<<(N + 3) / 4, 256, 0, stream>>>(
        mB, list_g, off_g, Wlg2gB, b_lg2g, 0, jkB + (size_t)2 * N * 64, N);
    // ---- linegraph layer 1: mB -> mA ----
    zero_fill<<<(int)((Eg * 8 + 255) / 256), 256, 0, stream>>>(off_lg, mA, Eg);
    edge_msg_lg2<<<(int)((Elg + 127) / 128), 512, 0, stream>>>(
        mB, eilg, ealg, WmsgLB + 9216, list_lg, mA, Elg);
    gather_gw<<<(N + 3) / 4, 256, 0, stream>>>(
        mA, list_g, off_g, Wlg2gB, b_lg2g, 0, jkB + (size_t)3 * N * 64, N);
    // ---- JK bidirectional LSTM ----
    {
        int ntiles = (N + 63) / 64;
        lstm3<<<dim3(ntiles, 2), 512, 0, stream>>>(
            jkB, WhhB, WihB, BS, W_att, scores, N);
    }
    final_kernel<<<(N + 3) / 4, 256, 0, stream>>>(
        jkB, scores, W_out, (float*)d_out, N);
}